// Round 3
// baseline (375.062 us; speedup 1.0000x reference)
//
#include <hip/hip_runtime.h>

#define B_   2
#define S_   2048
#define H_   2048
#define NH_  16
#define HS_  128
#define NORM_ 0.08838834764831845f          // 128^-0.5
#define L2B16 0.8304820237218407f           // log2(10000)/16

typedef unsigned short bf16_t;
typedef __bf16 bf16x8 __attribute__((ext_vector_type(8)));
typedef float  f32x4  __attribute__((ext_vector_type(4)));

__device__ __forceinline__ float b2f(bf16_t u) {
    return __uint_as_float(((unsigned int)u) << 16);
}
__device__ __forceinline__ bf16_t f2b(float f) {
    unsigned int x = __float_as_uint(f);
    x += 0x7fffu + ((x >> 16) & 1u);        // round-to-nearest-even
    return (bf16_t)(x >> 16);
}

__device__ __forceinline__ void async16(bf16_t* lds, const bf16_t* g) {
    __builtin_amdgcn_global_load_lds(
        (const __attribute__((address_space(1))) void*)g,
        (__attribute__((address_space(3))) void*)lds, 16, 0, 0);
}

__device__ __forceinline__ f32x4 mfma16(bf16x8 a, bf16x8 b, f32x4 c) {
    return __builtin_amdgcn_mfma_f32_16x16x32_bf16(a, b, c, 0, 0, 0);
}

#define BAR()        asm volatile("s_barrier" ::: "memory")
#define WAIT_LGKM0() asm volatile("s_waitcnt lgkmcnt(0)" ::: "memory")
#define WAIT_VM4()   asm volatile("s_waitcnt vmcnt(4)" ::: "memory")
#define WAIT_VM0()   asm volatile("s_waitcnt vmcnt(0)" ::: "memory")

// ---------------- f32 -> bf16 convert (8 elems/thread) ----------------
__global__ __launch_bounds__(256) void cvt_bf16(const float* __restrict__ in,
                                                bf16_t* __restrict__ out) {
    const size_t i = (size_t)blockIdx.x * 256 + threadIdx.x;
    const float4* p = (const float4*)in + i * 2;
    float4 a = p[0], b = p[1];
    bf16_t o[8] = { f2b(a.x), f2b(a.y), f2b(a.z), f2b(a.w),
                    f2b(b.x), f2b(b.y), f2b(b.z), f2b(b.w) };
    *((bf16x8*)out + i) = *(const bf16x8*)o;
}

// ---------------- W (KxN f32) -> W^T (NxK bf16), 32x32 tiles ----------------
__global__ __launch_bounds__(256) void transpose_cvt(const float* __restrict__ W,
                                                     bf16_t* __restrict__ WT,
                                                     int K, int N) {
    __shared__ float tile[32][33];
    const int tx = threadIdx.x & 31, ty = threadIdx.x >> 5;
    const int n0 = blockIdx.x * 32, k0 = blockIdx.y * 32;
#pragma unroll
    for (int i = 0; i < 4; i++)
        tile[ty + i * 8][tx] = W[(size_t)(k0 + ty + i * 8) * N + n0 + tx];
    __syncthreads();
#pragma unroll
    for (int i = 0; i < 4; i++)
        WT[(size_t)(n0 + ty + i * 8) * K + k0 + tx] = f2b(tile[tx][ty + i * 8]);
}

// ---------------- 256x256 8-phase GEMM: C = A(MxK) @ BT(NxK)^T + bias ------
// BK=64, 8 waves (2M x 4N), 128 KiB LDS (2 dbuf x (A 256x64 + B 256x64) bf16),
// XOR-swizzle (16B-chunk ^= row&7) on ds_read, inverse-swizzled global src for
// the linear global_load_lds staging. Counted vmcnt(4) at phases 4/8 only.
__device__ __forceinline__ void stage_half(bf16_t* lds, const bf16_t* g,
                                           int K, int half, int tid) {
#pragma unroll
    for (int j = 0; j < 2; j++) {
        const int idx = half * 1024 + j * 512 + tid;   // 16B-chunk index
        const int row = idx >> 3, slot = idx & 7;
        async16(lds + idx * 8,
                g + (size_t)row * K + ((slot ^ (row & 7)) << 3));
    }
}

#define PHASE(ab, bb, q, ISSUES, TAILW) do {                                   \
    if ((q) == 0) {                                                            \
        _Pragma("unroll")                                                      \
        for (int n = 0; n < 4; n++)                                            \
            _Pragma("unroll")                                                  \
            for (int ks = 0; ks < 2; ks++) {                                   \
                const int r = wn * 64 + n * 16 + lr;                           \
                bfr[n][ks] = *(const bf16x8*)                                  \
                    &(bb)[r * 64 + (((ks * 4 + ls) ^ (r & 7)) << 3)];          \
            }                                                                  \
    }                                                                          \
    bf16x8 af[2][2];                                                           \
    _Pragma("unroll")                                                          \
    for (int m = 0; m < 2; m++)                                                \
        _Pragma("unroll")                                                      \
        for (int ks = 0; ks < 2; ks++) {                                       \
            const int r = wm * 128 + (q) * 32 + m * 16 + lr;                   \
            af[m][ks] = *(const bf16x8*)                                       \
                &(ab)[r * 64 + (((ks * 4 + ls) ^ (r & 7)) << 3)];              \
        }                                                                      \
    ISSUES;                                                                    \
    BAR();                                                                     \
    WAIT_LGKM0();                                                              \
    __builtin_amdgcn_s_setprio(1);                                             \
    _Pragma("unroll")                                                          \
    for (int ks = 0; ks < 2; ks++)                                             \
        _Pragma("unroll")                                                      \
        for (int n = 0; n < 4; n++)                                            \
            _Pragma("unroll")                                                  \
            for (int m = 0; m < 2; m++)                                        \
                acc[(q) * 2 + m][n] =                                          \
                    mfma16(af[m][ks], bfr[n][ks], acc[(q) * 2 + m][n]);        \
    __builtin_amdgcn_s_setprio(0);                                             \
    TAILW;                                                                     \
    BAR();                                                                     \
} while (0)

template <int BF16OUT>
__global__ __launch_bounds__(512, 2) void gemm256(const bf16_t* __restrict__ A,
                                                  const bf16_t* __restrict__ BT,
                                                  const float* __restrict__ bias,
                                                  void* __restrict__ Cv,
                                                  int M, int N, int K) {
    __shared__ __align__(16) bf16_t As[2][256 * 64];
    __shared__ __align__(16) bf16_t Bs[2][256 * 64];

    // XCD-bijective block swizzle (grid size is a multiple of 8)
    const int nwg = (int)(gridDim.x * gridDim.y);
    const int id  = (int)(blockIdx.y * gridDim.x + blockIdx.x);
    const int wg  = (id & 7) * (nwg >> 3) + (id >> 3);
    const int bx  = wg % (int)gridDim.x, by = wg / (int)gridDim.x;

    const int tid = threadIdx.x;
    const int wid = tid >> 6, lane = tid & 63;
    const int lr = lane & 15, ls = lane >> 4;
    const int wm = wid >> 2, wn = wid & 3;
    const size_t m0 = (size_t)by * 256, n0 = (size_t)bx * 256;

    const bf16_t* Ab = A + m0 * K;
    const bf16_t* Bb = BT + n0 * K;

    f32x4 acc[8][4];
#pragma unroll
    for (int m = 0; m < 8; m++)
#pragma unroll
        for (int n = 0; n < 4; n++) acc[m][n] = (f32x4){0.f, 0.f, 0.f, 0.f};
    bf16x8 bfr[4][2];

    // prologue: tile0 A+B, tile1 B  (12 loads; vmcnt(4) leaves tile1-B in flight)
    stage_half(As[0], Ab, K, 0, tid);
    stage_half(As[0], Ab, K, 1, tid);
    stage_half(Bs[0], Bb, K, 0, tid);
    stage_half(Bs[0], Bb, K, 1, tid);
    stage_half(Bs[1], Bb + 64, K, 0, tid);
    stage_half(Bs[1], Bb + 64, K, 1, tid);
    WAIT_VM4();
    BAR();

    const int ni = (K >> 6) >> 1;            // iterations (2 K-tiles each)
#pragma unroll 1
    for (int i = 0; i < ni - 1; ++i) {
        const size_t kt1 = (size_t)(2 * i + 1) * 64;
        const size_t nt2 = (size_t)(2 * i + 2) * 64;
        const size_t nt3 = (size_t)(2 * i + 3) * 64;
        PHASE(As[0], Bs[0], 0, stage_half(As[1], Ab + kt1, K, 0, tid), );
        PHASE(As[0], Bs[0], 1,
              { stage_half(As[1], Ab + kt1, K, 1, tid);
                stage_half(Bs[0], Bb + nt2, K, 0, tid); }, );
        PHASE(As[0], Bs[0], 2, stage_half(Bs[0], Bb + nt2, K, 1, tid), );
        PHASE(As[0], Bs[0], 3, , WAIT_VM4());
        PHASE(As[1], Bs[1], 0, stage_half(As[0], Ab + nt2, K, 0, tid), );
        PHASE(As[1], Bs[1], 1,
              { stage_half(As[0], Ab + nt2, K, 1, tid);
                stage_half(Bs[1], Bb + nt3, K, 0, tid); }, );
        PHASE(As[1], Bs[1], 2, stage_half(Bs[1], Bb + nt3, K, 1, tid), );
        PHASE(As[1], Bs[1], 3, , WAIT_VM4());
    }
    {   // tail iteration: no future tiles; drain to 0 before second half
        const size_t kt1 = (size_t)(K - 64);
        PHASE(As[0], Bs[0], 0, stage_half(As[1], Ab + kt1, K, 0, tid), );
        PHASE(As[0], Bs[0], 1, stage_half(As[1], Ab + kt1, K, 1, tid), );
        PHASE(As[0], Bs[0], 2, , );
        PHASE(As[0], Bs[0], 3, , WAIT_VM0());
        PHASE(As[1], Bs[1], 0, , );
        PHASE(As[1], Bs[1], 1, , );
        PHASE(As[1], Bs[1], 2, , );
        PHASE(As[1], Bs[1], 3, , );
    }

    float bv[4];
#pragma unroll
    for (int n = 0; n < 4; n++) bv[n] = bias[n0 + wn * 64 + n * 16 + lr];
#pragma unroll
    for (int mm = 0; mm < 8; mm++)
#pragma unroll
        for (int n = 0; n < 4; n++)
#pragma unroll
            for (int j = 0; j < 4; j++) {
                const size_t row = m0 + wm * 128 + mm * 16 + ls * 4 + j;
                const size_t col = n0 + wn * 64 + n * 16 + lr;
                const float v = acc[mm][n][j] + bv[n];
                if (BF16OUT) ((bf16_t*)Cv)[row * N + col] = f2b(v);
                else         ((float*)Cv)[row * N + col] = v;
            }
}

// ---------------- RoPE + scatter to Q, K, V^T ----------------
__global__ __launch_bounds__(256) void rope_scatter(const bf16_t* __restrict__ qkv,
                                                    const int* __restrict__ pos_ids,
                                                    bf16_t* __restrict__ Qo,
                                                    bf16_t* __restrict__ Ko,
                                                    bf16_t* __restrict__ Vt) {
    const size_t gid = (size_t)blockIdx.x * 256 + threadIdx.x;
    const int d8 = (int)(gid & 15);
    const size_t t1 = gid >> 4;
    const int which = (int)(t1 % 3);
    const size_t t2 = t1 / 3;
    const int nh = (int)(t2 & 15);
    const size_t bs = t2 >> 4;                  // b*S + s
    const int s = (int)(bs & (S_ - 1));
    const int b = (int)(bs >> 11);

    const bf16_t* src = qkv + bs * (3 * H_) + nh * 384 + which * 128 + d8 * 8;
    bf16x8 xv = *(const bf16x8*)src;
    const bf16_t* xu = (const bf16_t*)&xv;

    if (which == 2) {                           // V: transpose to (bh, HS, S)
        bf16_t* vb = Vt + ((size_t)(b * NH_ + nh) * HS_ + d8 * 8) * S_ + s;
#pragma unroll
        for (int i = 0; i < 8; i++) vb[(size_t)i * S_] = xu[i];
        return;
    }
    float xf[8];
#pragma unroll
    for (int i = 0; i < 8; i++) xf[i] = b2f(xu[i]);
    const int d0 = d8 * 8;
    if (d0 < 32) {                              // rotary on first 32 dims
        const float pos = (float)pos_ids[bs];
        bf16x8 yv = *(const bf16x8*)(src + ((d0 < 16) ? 16 : -16));
        const bf16_t* yu = (const bf16_t*)&yv;
#pragma unroll
        for (int i = 0; i < 8; i++) {
            const int d = d0 + i;
            const float th = pos * exp2f(-(float)(d & 15) * L2B16);
            const float c = cosf(th), sn = sinf(th);
            const float rot = (d < 16) ? -b2f(yu[i]) : b2f(yu[i]);
            xf[i] = xf[i] * c + rot * sn;
        }
    }
    bf16_t ou[8];
#pragma unroll
    for (int i = 0; i < 8; i++) ou[i] = f2b(xf[i]);
    bf16_t* dst = ((which == 0) ? Qo : Ko) + ((size_t)(b * NH_ + nh) * S_ + s) * HS_ + d0;
    *(bf16x8*)dst = *(const bf16x8*)ou;
}

// ---------------- causal flash attention ----------------
__global__ __launch_bounds__(256) void attn_fwd(const bf16_t* __restrict__ Q,
                                                const bf16_t* __restrict__ Kv,
                                                const bf16_t* __restrict__ Vt,
                                                const float* __restrict__ amask,
                                                bf16_t* __restrict__ ctx) {
    __shared__ __align__(16) bf16_t Ks[64 * 128];
    __shared__ __align__(16) bf16_t Vs[128 * 64];
    __shared__ __align__(16) bf16_t Ps[4][16 * 72];

    const int id = (int)(blockIdx.x + (blockIdx.y << 4));     // 0..511
    const int wg = ((id & 7) << 6) + (id >> 3);               // XCD-bijective swizzle
    const int pair = wg & 15;
    const int bh = wg >> 4;
    const int b = bh >> 4, h = bh & 15;
    const int tid = threadIdx.x, wid = tid >> 6, lane = tid & 63;
    const int lr = lane & 15, ls = lane >> 4;
    const float* am = amask + (size_t)b * S_;

#pragma unroll 1
    for (int half = 0; half < 2; ++half) {
        const int qt = half ? pair : (31 - pair);
        const int q0 = qt << 6;

        bf16x8 qf[4];
        const bf16_t* qp = Q + ((size_t)bh * S_ + q0 + wid * 16 + lr) * HS_;
#pragma unroll
        for (int dk = 0; dk < 4; dk++) qf[dk] = *(const bf16x8*)(qp + dk * 32 + ls * 8);

        float mrun[4], lrun[4];
        f32x4 oacc[8];
#pragma unroll
        for (int j = 0; j < 4; j++) { mrun[j] = -3.0e38f; lrun[j] = 0.f; }
#pragma unroll
        for (int dt = 0; dt < 8; dt++) oacc[dt] = (f32x4){0.f, 0.f, 0.f, 0.f};

        const int qrb = q0 + wid * 16 + ls * 4;

#pragma unroll 1
        for (int step = 0; step <= qt; ++step) {
            const int kv0 = step << 6;
            __syncthreads();
#pragma unroll
            for (int jj = 0; jj < 4; jj++) {
                const int c = (wid << 2) + jj;
                const int rk = (c << 2) + (lane >> 4);        // K row 0..63
                async16(Ks + c * 512,
                        Kv + ((size_t)bh * S_ + kv0 + rk) * HS_
                           + (((lane & 15) ^ (rk & 7)) << 3));
                const int rv = (c << 3) + (lane >> 3);        // V^T row 0..127
                async16(Vs + c * 512,
                        Vt + ((size_t)bh * HS_ + rv) * S_ + kv0
                           + (((lane & 7) ^ (rv & 7)) << 3));
            }
            __syncthreads();

            f32x4 sacc[4];
#pragma unroll
            for (int t = 0; t < 4; t++) sacc[t] = (f32x4){0.f, 0.f, 0.f, 0.f};
#pragma unroll
            for (int t = 0; t < 4; t++)
#pragma unroll
                for (int dk = 0; dk < 4; dk++) {
                    const int row = t * 16 + lr;
                    bf16x8 kf = *(const bf16x8*)
                        &Ks[row * 128 + (((dk * 4 + ls) ^ (row & 7)) << 3)];
                    sacc[t] = mfma16(qf[dk], kf, sacc[t]);
                }

            const bool diag = (step == qt);
            float sv[4][4], rmax[4];
#pragma unroll
            for (int j = 0; j < 4; j++) {
#pragma unroll
                for (int t = 0; t < 4; t++) {
                    const int kvp = kv0 + t * 16 + lr;
                    float v = sacc[t][j] * NORM_ + am[kvp];
                    if (diag && kvp > qrb + j) v = -3.0e38f;
                    sv[t][j] = v;
                }
                rmax[j] = fmaxf(fmaxf(sv[0][j], sv[1][j]), fmaxf(sv[2][j], sv[3][j]));
            }
#pragma unroll
            for (int off = 1; off < 16; off <<= 1)
#pragma unroll
                for (int j = 0; j < 4; j++)
                    rmax[j] = fmaxf(rmax[j], __shfl_xor(rmax[j], off));

            float scj[4], psum[4];
#pragma unroll
            for (int j = 0; j < 4; j++) {
                const float mnew = fmaxf(mrun[j], rmax[j]);
                scj[j] = __expf(mrun[j] - mnew);
                mrun[j] = mnew;
                psum[j] = 0.f;
#pragma unroll
                for (int t = 0; t < 4; t++) {
                    const float p = __expf(sv[t][j] - mnew);
                    psum[j] += p;
                    Ps[wid][(ls * 4 + j) * 72 + t * 16 + lr] = f2b(p);
                }
            }
#pragma unroll
            for (int off = 1; off < 16; off <<= 1)
#pragma unroll
                for (int j = 0; j < 4; j++) psum[j] += __shfl_xor(psum[j], off);
#pragma unroll
            for (int j = 0; j < 4; j++) {
                lrun[j] = lrun[j] * scj[j] + psum[j];
#pragma unroll
                for (int dt = 0; dt < 8; dt++) oacc[dt][j] *= scj[j];
            }

            bf16x8 pf[2];
#pragma unroll
            for (int hh = 0; hh < 2; hh++)
                pf[hh] = *(const bf16x8*)&Ps[wid][lr * 72 + hh * 32 + ls * 8];
#pragma unroll
            for (int dt = 0; dt < 8; dt++)
#pragma unroll
                for (int hh = 0; hh < 2; hh++) {
                    const int vrow = dt * 16 + lr;
                    bf16x8 vf = *(const bf16x8*)
                        &Vs[vrow * 64 + (((hh * 4 + ls) ^ (vrow & 7)) << 3)];
                    oacc[dt] = mfma16(pf[hh], vf, oacc[dt]);
                }
        }

#pragma unroll
        for (int j = 0; j < 4; j++) {
            const float inv = 1.0f / lrun[j];
            bf16_t* dst = ctx + ((size_t)b * S_ + q0 + wid * 16 + ls * 4 + j) * H_ + h * HS_;
#pragma unroll
            for (int dt = 0; dt < 8; dt++) dst[dt * 16 + lr] = f2b(oacc[dt][j] * inv);
        }
    }
}

extern "C" void kernel_launch(void* const* d_in, const int* in_sizes, int n_in,
                              void* d_out, int out_size, void* d_ws, size_t ws_size,
                              hipStream_t stream) {
    const float* hs   = (const float*)d_in[0];
    const float* am   = (const float*)d_in[1];
    const int*   pos  = (const int*)d_in[2];
    const float* Wqkv = (const float*)d_in[3];
    const float* bqkv = (const float*)d_in[4];
    const float* Wd   = (const float*)d_in[5];
    const float* bd   = (const float*)d_in[6];
    float* out = (float*)d_out;
    char*  ws  = (char*)d_ws;

    const size_t MB = 1024 * 1024;
    bf16_t* X    = (bf16_t*)(ws);              // 16 MB (reused as ctx)
    bf16_t* WqT  = (bf16_t*)(ws + 16 * MB);    // 24 MB
    bf16_t* WdT  = (bf16_t*)(ws + 40 * MB);    // 8 MB
    bf16_t* QKVb = (bf16_t*)(ws + 48 * MB);    // 48 MB
    bf16_t* Qb   = (bf16_t*)(ws + 96 * MB);    // 16 MB
    bf16_t* Kb   = (bf16_t*)(ws + 112 * MB);   // 16 MB
    bf16_t* Vtb  = (bf16_t*)(ws + 128 * MB);   // 16 MB
    bf16_t* ctx  = X;

    cvt_bf16<<<4096, 256, 0, stream>>>(hs, X);
    transpose_cvt<<<dim3(6144 / 32, 2048 / 32), 256, 0, stream>>>(Wqkv, WqT, 2048, 6144);
    transpose_cvt<<<dim3(2048 / 32, 2048 / 32), 256, 0, stream>>>(Wd, WdT, 2048, 2048);
    gemm256<1><<<dim3(24, 16), 512, 0, stream>>>(X, WqT, bqkv, QKVb, 4096, 6144, 2048);
    rope_scatter<<<12288, 256, 0, stream>>>(QKVb, pos, Qb, Kb, Vtb);
    attn_fwd<<<dim3(16, 32), 256, 0, stream>>>(Qb, Kb, Vtb, am, ctx);
    gemm256<0><<<dim3(8, 16), 512, 0, stream>>>(ctx, WdT, bd, out, 4096, 2048, 2048);
}

// Round 4
// 347.493 us; speedup vs baseline: 1.0793x; 1.0793x over previous
//
#include <hip/hip_runtime.h>

#define B_   2
#define S_   2048
#define H_   2048
#define NH_  16
#define HS_  128
#define NORM_ 0.08838834764831845f          // 128^-0.5
#define L2B16 0.8304820237218407f           // log2(10000)/16

typedef unsigned short bf16_t;
typedef __bf16 bf16x8 __attribute__((ext_vector_type(8)));
typedef float  f32x4  __attribute__((ext_vector_type(4)));

__device__ __forceinline__ float b2f(bf16_t u) {
    return __uint_as_float(((unsigned int)u) << 16);
}
__device__ __forceinline__ bf16_t f2b(float f) {
    unsigned int x = __float_as_uint(f);
    x += 0x7fffu + ((x >> 16) & 1u);        // round-to-nearest-even
    return (bf16_t)(x >> 16);
}

__device__ __forceinline__ void async16(bf16_t* lds, const bf16_t* g) {
    __builtin_amdgcn_global_load_lds(
        (const __attribute__((address_space(1))) void*)g,
        (__attribute__((address_space(3))) void*)lds, 16, 0, 0);
}

__device__ __forceinline__ f32x4 mfma16(bf16x8 a, bf16x8 b, f32x4 c) {
    return __builtin_amdgcn_mfma_f32_16x16x32_bf16(a, b, c, 0, 0, 0);
}

#define BAR()        asm volatile("s_barrier" ::: "memory")
#define WAIT_LGKM0() asm volatile("s_waitcnt lgkmcnt(0)" ::: "memory")
#define WAIT_VM0()   asm volatile("s_waitcnt vmcnt(0)" ::: "memory")
#define WAIT_VM3()   asm volatile("s_waitcnt vmcnt(3)" ::: "memory")
#define WAIT_VM8()   asm volatile("s_waitcnt vmcnt(8)" ::: "memory")

// ---------------- f32 -> bf16 convert (8 elems/thread) ----------------
__global__ __launch_bounds__(256) void cvt_bf16(const float* __restrict__ in,
                                                bf16_t* __restrict__ out) {
    const size_t i = (size_t)blockIdx.x * 256 + threadIdx.x;
    const float4* p = (const float4*)in + i * 2;
    float4 a = p[0], b = p[1];
    bf16_t o[8] = { f2b(a.x), f2b(a.y), f2b(a.z), f2b(a.w),
                    f2b(b.x), f2b(b.y), f2b(b.z), f2b(b.w) };
    *((bf16x8*)out + i) = *(const bf16x8*)o;
}

// ---------------- W (KxN f32) -> W^T (NxK bf16), 32x32 tiles ----------------
__global__ __launch_bounds__(256) void transpose_cvt(const float* __restrict__ W,
                                                     bf16_t* __restrict__ WT,
                                                     int K, int N) {
    __shared__ float tile[32][33];
    const int tx = threadIdx.x & 31, ty = threadIdx.x >> 5;
    const int n0 = blockIdx.x * 32, k0 = blockIdx.y * 32;
#pragma unroll
    for (int i = 0; i < 4; i++)
        tile[ty + i * 8][tx] = W[(size_t)(k0 + ty + i * 8) * N + n0 + tx];
    __syncthreads();
#pragma unroll
    for (int i = 0; i < 4; i++)
        WT[(size_t)(n0 + ty + i * 8) * K + k0 + tx] = f2b(tile[tx][ty + i * 8]);
}

// ---------------- 128x128 2-phase GEMM (proven; used for dense) ------------
template <int BF16OUT>
__global__ __launch_bounds__(256) void gemm_bias(const bf16_t* __restrict__ A,
                                                 const bf16_t* __restrict__ BT,
                                                 const float* __restrict__ bias,
                                                 void* __restrict__ Cv,
                                                 int M, int N, int K) {
    __shared__ __align__(16) bf16_t As[128 * 32];
    __shared__ __align__(16) bf16_t Bs[128 * 32];
    const int tid = threadIdx.x;
    const int wid = tid >> 6, lane = tid & 63;
    const int lr = lane & 15, ls = lane >> 4;
    const int wr = wid >> 1, wc = wid & 1;
    const size_t m0 = (size_t)blockIdx.y * 128, n0 = (size_t)blockIdx.x * 128;

    f32x4 acc[4][4];
#pragma unroll
    for (int m = 0; m < 4; m++)
#pragma unroll
        for (int n = 0; n < 4; n++) acc[m][n] = (f32x4){0.f, 0.f, 0.f, 0.f};

    const int srow = lane >> 2, sk = (lane & 3) * 8;

    for (int k0 = 0; k0 < K; k0 += 32) {
        __syncthreads();
#pragma unroll
        for (int j = 0; j < 2; j++) {
            const int rr = (wid * 2 + j) * 16 + srow;
            async16(As + (wid * 2 + j) * 512, A + (m0 + rr) * K + k0 + sk);
            async16(Bs + (wid * 2 + j) * 512, BT + (n0 + rr) * K + k0 + sk);
        }
        __syncthreads();
        bf16x8 af[4], bfr[4];
#pragma unroll
        for (int m = 0; m < 4; m++)
            af[m] = *(const bf16x8*)&As[(wr * 64 + m * 16 + lr) * 32 + ls * 8];
#pragma unroll
        for (int n = 0; n < 4; n++)
            bfr[n] = *(const bf16x8*)&Bs[(wc * 64 + n * 16 + lr) * 32 + ls * 8];
#pragma unroll
        for (int m = 0; m < 4; m++)
#pragma unroll
            for (int n = 0; n < 4; n++)
                acc[m][n] = mfma16(af[m], bfr[n], acc[m][n]);
    }

    float bv[4];
#pragma unroll
    for (int n = 0; n < 4; n++) bv[n] = bias[n0 + wc * 64 + n * 16 + lr];
#pragma unroll
    for (int m = 0; m < 4; m++)
#pragma unroll
        for (int n = 0; n < 4; n++)
#pragma unroll
            for (int j = 0; j < 4; j++) {
                const size_t row = m0 + wr * 64 + m * 16 + ls * 4 + j;
                const size_t col = n0 + wc * 64 + n * 16 + lr;
                const float v = acc[m][n][j] + bv[n];
                if (BF16OUT) ((bf16_t*)Cv)[row * N + col] = f2b(v);
                else         ((float*)Cv)[row * N + col] = v;
            }
}

// ---------------- 256x192 8-phase GEMM (QKV): C = A @ BT^T + bias ----------
// BK=64, 8 waves (2M x 4N, per-wave 128x48), 112 KiB LDS double-buffered.
// 7 staging calls/thread per K-tile (A: 4x512-chunk, B: 3x512-chunk).
// Counted vmcnt(3) at phases 4/8; XOR chunk^(row&7) swizzle both sides.
__device__ __forceinline__ void st512(bf16_t* lds, const bf16_t* g,
                                      int K, int part, int tid) {
    const int idx = part * 512 + tid;
    const int row = idx >> 3, slot = idx & 7;
    async16(lds + idx * 8, g + (size_t)row * K + ((slot ^ (row & 7)) << 3));
}

#define PHASE3(ab, bb, q, ISSUES, TAILW) do {                                  \
    if ((q) == 0) {                                                            \
        _Pragma("unroll")                                                      \
        for (int n = 0; n < 3; n++)                                            \
            _Pragma("unroll")                                                  \
            for (int ks = 0; ks < 2; ks++) {                                   \
                const int r = wn * 48 + n * 16 + lr;                           \
                bfr[n][ks] = *(const bf16x8*)                                  \
                    &(bb)[r * 64 + (((ks * 4 + ls) ^ (r & 7)) << 3)];          \
            }                                                                  \
    }                                                                          \
    bf16x8 af[2][2];                                                           \
    _Pragma("unroll")                                                          \
    for (int m = 0; m < 2; m++)                                                \
        _Pragma("unroll")                                                      \
        for (int ks = 0; ks < 2; ks++) {                                       \
            const int r = wm * 128 + (q) * 32 + m * 16 + lr;                   \
            af[m][ks] = *(const bf16x8*)                                       \
                &(ab)[r * 64 + (((ks * 4 + ls) ^ (r & 7)) << 3)];              \
        }                                                                      \
    ISSUES;                                                                    \
    BAR();                                                                     \
    WAIT_LGKM0();                                                              \
    __builtin_amdgcn_s_setprio(1);                                             \
    _Pragma("unroll")                                                          \
    for (int ks = 0; ks < 2; ks++)                                             \
        _Pragma("unroll")                                                      \
        for (int n = 0; n < 3; n++)                                            \
            _Pragma("unroll")                                                  \
            for (int m = 0; m < 2; m++)                                        \
                acc[(q) * 2 + m][n] =                                          \
                    mfma16(af[m][ks], bfr[n][ks], acc[(q) * 2 + m][n]);        \
    __builtin_amdgcn_s_setprio(0);                                             \
    TAILW;                                                                     \
    BAR();                                                                     \
} while (0)

__global__ __launch_bounds__(512, 2) void gemm256x192(const bf16_t* __restrict__ A,
                                                      const bf16_t* __restrict__ BT,
                                                      const float* __restrict__ bias,
                                                      bf16_t* __restrict__ C,
                                                      int M, int N, int K) {
    __shared__ __align__(16) bf16_t As[2][256 * 64];
    __shared__ __align__(16) bf16_t Bs[2][192 * 64];

    const int nwg = (int)(gridDim.x * gridDim.y);
    const int id  = (int)(blockIdx.y * gridDim.x + blockIdx.x);
    const int wg  = (id & 7) * (nwg >> 3) + (id >> 3);      // XCD-bijective
    const int bx  = wg % (int)gridDim.x, by = wg / (int)gridDim.x;

    const int tid = threadIdx.x;
    const int wid = tid >> 6, lane = tid & 63;
    const int lr = lane & 15, ls = lane >> 4;
    const int wm = wid >> 2, wn = wid & 3;
    const size_t m0 = (size_t)by * 256, n0 = (size_t)bx * 192;

    const bf16_t* Ab = A + m0 * K;
    const bf16_t* Bb = BT + n0 * K;

    f32x4 acc[8][3];
#pragma unroll
    for (int m = 0; m < 8; m++)
#pragma unroll
        for (int n = 0; n < 3; n++) acc[m][n] = (f32x4){0.f, 0.f, 0.f, 0.f};
    bf16x8 bfr[3][2];

    // prologue: A0(4) B0(3) B1(3); vmcnt(3) leaves B1 in flight
#pragma unroll
    for (int p = 0; p < 4; p++) st512(As[0], Ab, K, p, tid);
#pragma unroll
    for (int p = 0; p < 3; p++) st512(Bs[0], Bb, K, p, tid);
#pragma unroll
    for (int p = 0; p < 3; p++) st512(Bs[1], Bb + 64, K, p, tid);
    WAIT_VM3();
    BAR();

    const int ni = (K >> 6) >> 1;
#pragma unroll 1
    for (int i = 0; i < ni - 1; ++i) {
        const size_t t1 = (size_t)(2 * i + 1) * 64;
        const size_t t2 = (size_t)(2 * i + 2) * 64;
        const size_t t3 = (size_t)(2 * i + 3) * 64;
        PHASE3(As[0], Bs[0], 0,
               { st512(As[1], Ab + t1, K, 0, tid); st512(As[1], Ab + t1, K, 1, tid); }, );
        PHASE3(As[0], Bs[0], 1,
               { st512(As[1], Ab + t1, K, 2, tid); st512(As[1], Ab + t1, K, 3, tid); }, );
        PHASE3(As[0], Bs[0], 2,
               { st512(Bs[0], Bb + t2, K, 0, tid); st512(Bs[0], Bb + t2, K, 1, tid); }, );
        PHASE3(As[0], Bs[0], 3, st512(Bs[0], Bb + t2, K, 2, tid), WAIT_VM3());
        PHASE3(As[1], Bs[1], 0,
               { st512(As[0], Ab + t2, K, 0, tid); st512(As[0], Ab + t2, K, 1, tid); }, );
        PHASE3(As[1], Bs[1], 1,
               { st512(As[0], Ab + t2, K, 2, tid); st512(As[0], Ab + t2, K, 3, tid); }, );
        PHASE3(As[1], Bs[1], 2,
               { st512(Bs[1], Bb + t3, K, 0, tid); st512(Bs[1], Bb + t3, K, 1, tid); }, );
        PHASE3(As[1], Bs[1], 3, st512(Bs[1], Bb + t3, K, 2, tid), WAIT_VM3());
    }
    {   // tail iteration
        const size_t t1 = (size_t)(K - 64);
        PHASE3(As[0], Bs[0], 0,
               { st512(As[1], Ab + t1, K, 0, tid); st512(As[1], Ab + t1, K, 1, tid); }, );
        PHASE3(As[0], Bs[0], 1,
               { st512(As[1], Ab + t1, K, 2, tid); st512(As[1], Ab + t1, K, 3, tid); }, );
        PHASE3(As[0], Bs[0], 2, , );
        PHASE3(As[0], Bs[0], 3, , WAIT_VM0());
        PHASE3(As[1], Bs[1], 0, , );
        PHASE3(As[1], Bs[1], 1, , );
        PHASE3(As[1], Bs[1], 2, , );
        PHASE3(As[1], Bs[1], 3, , );
    }

    float bv[3];
#pragma unroll
    for (int n = 0; n < 3; n++) bv[n] = bias[n0 + wn * 48 + n * 16 + lr];
#pragma unroll
    for (int mm = 0; mm < 8; mm++)
#pragma unroll
        for (int n = 0; n < 3; n++)
#pragma unroll
            for (int j = 0; j < 4; j++) {
                const size_t row = m0 + wm * 128 + mm * 16 + ls * 4 + j;
                const size_t col = n0 + wn * 48 + n * 16 + lr;
                C[row * N + col] = f2b(acc[mm][n][j] + bv[n]);
            }
}

// ---------------- RoPE on Q,K only (pow-2 indexing) ----------------
__global__ __launch_bounds__(256) void rope_qk(const bf16_t* __restrict__ qkv,
                                               const int* __restrict__ pos_ids,
                                               bf16_t* __restrict__ Qo,
                                               bf16_t* __restrict__ Ko) {
    const size_t gid = (size_t)blockIdx.x * 256 + threadIdx.x;
    const int d8 = (int)(gid & 15);
    const size_t t1 = gid >> 4;
    const int which = (int)(t1 & 1);
    const size_t t2 = t1 >> 1;
    const int nh = (int)(t2 & 15);
    const size_t bs = t2 >> 4;                  // b*S + s
    const int s = (int)(bs & (S_ - 1));
    const int b = (int)(bs >> 11);

    const bf16_t* src = qkv + bs * (3 * H_) + nh * 384 + which * 128 + d8 * 8;
    bf16x8 xv = *(const bf16x8*)src;
    const bf16_t* xu = (const bf16_t*)&xv;

    float xf[8];
#pragma unroll
    for (int i = 0; i < 8; i++) xf[i] = b2f(xu[i]);
    const int d0 = d8 * 8;
    if (d0 < 32) {                              // rotary on first 32 dims
        const float pos = (float)pos_ids[bs];
        bf16x8 yv = *(const bf16x8*)(src + ((d0 < 16) ? 16 : -16));
        const bf16_t* yu = (const bf16_t*)&yv;
#pragma unroll
        for (int i = 0; i < 8; i++) {
            const int d = d0 + i;
            const float th = pos * exp2f(-(float)(d & 15) * L2B16);
            const float c = cosf(th), sn = sinf(th);
            const float rot = (d < 16) ? -b2f(yu[i]) : b2f(yu[i]);
            xf[i] = xf[i] * c + rot * sn;
        }
    }
    bf16_t ou[8];
#pragma unroll
    for (int i = 0; i < 8; i++) ou[i] = f2b(xf[i]);
    bf16_t* dst = ((which == 0) ? Qo : Ko) + ((size_t)(b * NH_ + nh) * S_ + s) * HS_ + d0;
    *(bf16x8*)dst = *(const bf16x8*)ou;
}

// ---------------- V transpose: (b,s,h,d) -> (bh, d, s), LDS-tiled ----------
// block: (bh, s-tile 128). LDS [128][130]: 130/2=65===1 mod 32 -> column reads
// have bank-stride 1 (conflict-free); row b128 writes are 2-way (free).
__global__ __launch_bounds__(256) void vxpose(const bf16_t* __restrict__ qkv,
                                              bf16_t* __restrict__ Vt) {
    __shared__ bf16_t t[128][130];
    const int bh = (int)blockIdx.x >> 4;
    const int s0 = ((int)blockIdx.x & 15) << 7;
    const int b = bh >> 4, h = bh & 15;
    const int tid = threadIdx.x;

    // read: 16 lanes cover one row's 128 d (256B contiguous)
    const int dc = tid & 15, sl = tid >> 4;     // sl 0..15
    const bf16_t* src = qkv + ((size_t)b * S_ + s0) * (3 * H_) + h * 384 + 256 + dc * 8;
#pragma unroll
    for (int c = 0; c < 8; c++) {
        const int s = sl + c * 16;
        bf16x8 v = *(const bf16x8*)(src + (size_t)s * (3 * H_));
        *(bf16x8*)&t[s][dc * 8] = v;
    }
    __syncthreads();
    // write: row d, 16 lanes cover 128 s (256B contiguous)
    const int sc = tid & 15, dl = tid >> 4;     // dl 0..15
    bf16_t* dst = Vt + ((size_t)bh * HS_) * S_ + s0 + sc * 8;
#pragma unroll
    for (int c = 0; c < 8; c++) {
        const int d = dl + c * 16;
        bf16_t o[8];
#pragma unroll
        for (int i = 0; i < 8; i++) o[i] = t[sc * 8 + i][d];
        *(bf16x8*)(dst + (size_t)d * S_) = *(const bf16x8*)o;
    }
}

// ---------------- causal flash attention (dbuf K/V, counted vmcnt) ----------
__device__ __forceinline__ void attn_stage(bf16_t* Kd, bf16_t* Vd,
                                           const bf16_t* Kg, const bf16_t* Vg,
                                           int kv0, int wid, int lane) {
#pragma unroll
    for (int jj = 0; jj < 4; jj++) {
        const int c = (wid << 2) + jj;
        const int rk = (c << 2) + (lane >> 4);        // K row 0..63
        async16(Kd + c * 512,
                Kg + (size_t)(kv0 + rk) * HS_ + (((lane & 15) ^ (rk & 7)) << 3));
        const int rv = (c << 3) + (lane >> 3);        // V^T row 0..127
        async16(Vd + c * 512,
                Vg + (size_t)rv * S_ + kv0 + (((lane & 7) ^ (rv & 7)) << 3));
    }
}

__global__ __launch_bounds__(256) void attn_fwd(const bf16_t* __restrict__ Q,
                                                const bf16_t* __restrict__ Kv,
                                                const bf16_t* __restrict__ Vt,
                                                const float* __restrict__ amask,
                                                bf16_t* __restrict__ ctx) {
    __shared__ __align__(16) bf16_t Ks[2][64 * 128];
    __shared__ __align__(16) bf16_t Vs[2][128 * 64];
    __shared__ __align__(16) bf16_t Ps[4][16 * 72];

    const int id = (int)(blockIdx.x + (blockIdx.y << 4));     // 0..511
    const int wg = ((id & 7) << 6) + (id >> 3);               // XCD-bijective
    const int pair = wg & 15;
    const int bh = wg >> 4;
    const int b = bh >> 4, h = bh & 15;
    const int tid = threadIdx.x, wid = tid >> 6, lane = tid & 63;
    const int lr = lane & 15, ls = lane >> 4;
    const float* am = amask + (size_t)b * S_;
    const bf16_t* Kg = Kv + (size_t)bh * S_ * HS_;
    const bf16_t* Vg = Vt + (size_t)bh * HS_ * S_;

#pragma unroll 1
    for (int half = 0; half < 2; ++half) {
        const int qt = half ? pair : (31 - pair);
        const int q0 = qt << 6;

        bf16x8 qf[4];
        const bf16_t* qp = Q + ((size_t)bh * S_ + q0 + wid * 16 + lr) * HS_;
#pragma unroll
        for (int dk = 0; dk < 4; dk++) qf[dk] = *(const bf16x8*)(qp + dk * 32 + ls * 8);

        float mrun[4], lrun[4];
        f32x4 oacc[8];
#pragma unroll
        for (int j = 0; j < 4; j++) { mrun[j] = -3.0e38f; lrun[j] = 0.f; }
#pragma unroll
        for (int dt = 0; dt < 8; dt++) oacc[dt] = (f32x4){0.f, 0.f, 0.f, 0.f};

        const int qrb = q0 + wid * 16 + ls * 4;

        attn_stage(Ks[0], Vs[0], Kg, Vg, 0, wid, lane);

#pragma unroll 1
        for (int step = 0; step <= qt; ++step) {
            const int cur = step & 1;
            const int kv0 = step << 6;
            if (step < qt) {
                attn_stage(Ks[cur ^ 1], Vs[cur ^ 1], Kg, Vg, (step + 1) << 6, wid, lane);
                WAIT_VM8();
            } else {
                WAIT_VM0();
            }
            BAR();

            f32x4 sacc[4];
#pragma unroll
            for (int t = 0; t < 4; t++) sacc[t] = (f32x4){0.f, 0.f, 0.f, 0.f};
#pragma unroll
            for (int t = 0; t < 4; t++)
#pragma unroll
                for (int dk = 0; dk < 4; dk++) {
                    const int row = t * 16 + lr;
                    bf16x8 kf = *(const bf16x8*)
                        &Ks[cur][row * 128 + (((dk * 4 + ls) ^ (row & 7)) << 3)];
                    sacc[t] = mfma16(qf[dk], kf, sacc[t]);
                }

            const bool diag = (step == qt);
            float sv[4][4], rmax[4];
#pragma unroll
            for (int j = 0; j < 4; j++) {
#pragma unroll
                for (int t = 0; t < 4; t++) {
                    const int kvp = kv0 + t * 16 + lr;
                    float v = sacc[t][j] * NORM_ + am[kvp];
                    if (diag && kvp > qrb + j) v = -3.0e38f;
                    sv[t][j] = v;
                }
                rmax[j] = fmaxf(fmaxf(sv[0][j], sv[1][j]), fmaxf(sv[2][j], sv[3][j]));
            }
#pragma unroll
            for (int off = 1; off < 16; off <<= 1)
#pragma unroll
                for (int j = 0; j < 4; j++)
                    rmax[j] = fmaxf(rmax[j], __shfl_xor(rmax[j], off));

            float scj[4], psum[4];
#pragma unroll
            for (int j = 0; j < 4; j++) {
                const float mnew = fmaxf(mrun[j], rmax[j]);
                scj[j] = __expf(mrun[j] - mnew);
                mrun[j] = mnew;
                psum[j] = 0.f;
#pragma unroll
                for (int t = 0; t < 4; t++) {
                    const float p = __expf(sv[t][j] - mnew);
                    psum[j] += p;
                    Ps[wid][(ls * 4 + j) * 72 + t * 16 + lr] = f2b(p);
                }
            }
#pragma unroll
            for (int off = 1; off < 16; off <<= 1)
#pragma unroll
                for (int j = 0; j < 4; j++) psum[j] += __shfl_xor(psum[j], off);
#pragma unroll
            for (int j = 0; j < 4; j++) {
                lrun[j] = lrun[j] * scj[j] + psum[j];
#pragma unroll
                for (int dt = 0; dt < 8; dt++) oacc[dt][j] *= scj[j];
            }

            bf16x8 pf[2];
#pragma unroll
            for (int hh = 0; hh < 2; hh++)
                pf[hh] = *(const bf16x8*)&Ps[wid][lr * 72 + hh * 32 + ls * 8];
#pragma unroll
            for (int dt = 0; dt < 8; dt++)
#pragma unroll
                for (int hh = 0; hh < 2; hh++) {
                    const int vrow = dt * 16 + lr;
                    bf16x8 vf = *(const bf16x8*)
                        &Vs[cur][vrow * 64 + (((hh * 4 + ls) ^ (vrow & 7)) << 3)];
                    oacc[dt] = mfma16(pf[hh], vf, oacc[dt]);
                }
            BAR();
        }

#pragma unroll
        for (int j = 0; j < 4; j++) {
            const float inv = 1.0f / lrun[j];
            bf16_t* dst = ctx + ((size_t)b * S_ + q0 + wid * 16 + ls * 4 + j) * H_ + h * HS_;
#pragma unroll
            for (int dt = 0; dt < 8; dt++) dst[dt * 16 + lr] = f2b(oacc[dt][j] * inv);
        }
    }
}

extern "C" void kernel_launch(void* const* d_in, const int* in_sizes, int n_in,
                              void* d_out, int out_size, void* d_ws, size_t ws_size,
                              hipStream_t stream) {
    const float* hs   = (const float*)d_in[0];
    const float* am   = (const float*)d_in[1];
    const int*   pos  = (const int*)d_in[2];
    const float* Wqkv = (const float*)d_in[3];
    const float* bqkv = (const float*)d_in[4];
    const float* Wd   = (const float*)d_in[5];
    const float* bd   = (const float*)d_in[6];
    float* out = (float*)d_out;
    char*  ws  = (char*)d_ws;

    const size_t MB = 1024 * 1024;
    bf16_t* X    = (bf16_t*)(ws);              // 16 MB (reused as ctx)
    bf16_t* WqT  = (bf16_t*)(ws + 16 * MB);    // 24 MB
    bf16_t* WdT  = (bf16_t*)(ws + 40 * MB);    // 8 MB
    bf16_t* QKVb = (bf16_t*)(ws + 48 * MB);    // 48 MB
    bf16_t* Qb   = (bf16_t*)(ws + 96 * MB);    // 16 MB
    bf16_t* Kb   = (bf16_t*)(ws + 112 * MB);   // 16 MB
    bf16_t* Vtb  = (bf16_t*)(ws + 128 * MB);   // 16 MB
    bf16_t* ctx  = X;

    cvt_bf16<<<4096, 256, 0, stream>>>(hs, X);
    transpose_cvt<<<dim3(6144 / 32, 2048 / 32), 256, 0, stream>>>(Wqkv, WqT, 2048, 6144);
    transpose_cvt<<<dim3(2048 / 32, 2048 / 32), 256, 0, stream>>>(Wd, WdT, 2048, 2048);
    gemm256x192<<<dim3(32, 16), 512, 0, stream>>>(X, WqT, bqkv, QKVb, 4096, 6144, 2048);
    rope_qk<<<8192, 256, 0, stream>>>(QKVb, pos, Qb, Kb);
    vxpose<<<512, 256, 0, stream>>>(QKVb, Vtb);
    attn_fwd<<<dim3(16, 32), 256, 0, stream>>>(Qb, Kb, Vtb, am, ctx);
    gemm_bias<0><<<dim3(2048 / 128, 4096 / 128), 256, 0, stream>>>(ctx, WdT, bd, out,
                                                                   4096, 2048, 2048);
}

// Round 5
// 337.002 us; speedup vs baseline: 1.1129x; 1.0311x over previous
//
#include <hip/hip_runtime.h>

#define B_   2
#define S_   2048
#define H_   2048
#define NH_  16
#define HS_  128
#define NORM_ 0.08838834764831845f          // 128^-0.5
#define L2B16 0.8304820237218407f           // log2(10000)/16

typedef unsigned short bf16_t;
typedef __bf16 bf16x8 __attribute__((ext_vector_type(8)));
typedef float  f32x4  __attribute__((ext_vector_type(4)));

__device__ __forceinline__ float b2f(bf16_t u) {
    return __uint_as_float(((unsigned int)u) << 16);
}
__device__ __forceinline__ bf16_t f2b(float f) {
    unsigned int x = __float_as_uint(f);
    x += 0x7fffu + ((x >> 16) & 1u);        // round-to-nearest-even
    return (bf16_t)(x >> 16);
}

__device__ __forceinline__ void async16(bf16_t* lds, const bf16_t* g) {
    __builtin_amdgcn_global_load_lds(
        (const __attribute__((address_space(1))) void*)g,
        (__attribute__((address_space(3))) void*)lds, 16, 0, 0);
}

__device__ __forceinline__ f32x4 mfma16(bf16x8 a, bf16x8 b, f32x4 c) {
    return __builtin_amdgcn_mfma_f32_16x16x32_bf16(a, b, c, 0, 0, 0);
}

#define BAR()        asm volatile("s_barrier" ::: "memory")
#define WAIT_VM0()   asm volatile("s_waitcnt vmcnt(0)" ::: "memory")
#define WAIT_VM3()   asm volatile("s_waitcnt vmcnt(3)" ::: "memory")
#define WAIT_VM8()   asm volatile("s_waitcnt vmcnt(8)" ::: "memory")

// ---------------- f32 -> bf16 convert (8 elems/thread) ----------------
__global__ __launch_bounds__(256) void cvt_bf16(const float* __restrict__ in,
                                                bf16_t* __restrict__ out) {
    const size_t i = (size_t)blockIdx.x * 256 + threadIdx.x;
    const float4* p = (const float4*)in + i * 2;
    float4 a = p[0], b = p[1];
    bf16_t o[8] = { f2b(a.x), f2b(a.y), f2b(a.z), f2b(a.w),
                    f2b(b.x), f2b(b.y), f2b(b.z), f2b(b.w) };
    *((bf16x8*)out + i) = *(const bf16x8*)o;
}

// ---------------- W (KxN f32) -> W^T (NxK bf16), 32x32 tiles ----------------
__global__ __launch_bounds__(256) void transpose_cvt(const float* __restrict__ W,
                                                     bf16_t* __restrict__ WT,
                                                     int K, int N) {
    __shared__ float tile[32][33];
    const int tx = threadIdx.x & 31, ty = threadIdx.x >> 5;
    const int n0 = blockIdx.x * 32, k0 = blockIdx.y * 32;
#pragma unroll
    for (int i = 0; i < 4; i++)
        tile[ty + i * 8][tx] = W[(size_t)(k0 + ty + i * 8) * N + n0 + tx];
    __syncthreads();
#pragma unroll
    for (int i = 0; i < 4; i++)
        WT[(size_t)(n0 + ty + i * 8) * K + k0 + tx] = f2b(tile[tx][ty + i * 8]);
}

// ---------------- 128x128 2-phase GEMM (proven; used for dense) ------------
template <int BF16OUT>
__global__ __launch_bounds__(256) void gemm_bias(const bf16_t* __restrict__ A,
                                                 const bf16_t* __restrict__ BT,
                                                 const float* __restrict__ bias,
                                                 void* __restrict__ Cv,
                                                 int M, int N, int K) {
    __shared__ __align__(16) bf16_t As[128 * 32];
    __shared__ __align__(16) bf16_t Bs[128 * 32];
    const int tid = threadIdx.x;
    const int wid = tid >> 6, lane = tid & 63;
    const int lr = lane & 15, ls = lane >> 4;
    const int wr = wid >> 1, wc = wid & 1;
    const size_t m0 = (size_t)blockIdx.y * 128, n0 = (size_t)blockIdx.x * 128;

    f32x4 acc[4][4];
#pragma unroll
    for (int m = 0; m < 4; m++)
#pragma unroll
        for (int n = 0; n < 4; n++) acc[m][n] = (f32x4){0.f, 0.f, 0.f, 0.f};

    const int srow = lane >> 2, sk = (lane & 3) * 8;

    for (int k0 = 0; k0 < K; k0 += 32) {
        __syncthreads();
#pragma unroll
        for (int j = 0; j < 2; j++) {
            const int rr = (wid * 2 + j) * 16 + srow;
            async16(As + (wid * 2 + j) * 512, A + (m0 + rr) * K + k0 + sk);
            async16(Bs + (wid * 2 + j) * 512, BT + (n0 + rr) * K + k0 + sk);
        }
        __syncthreads();
        bf16x8 af[4], bfr[4];
#pragma unroll
        for (int m = 0; m < 4; m++)
            af[m] = *(const bf16x8*)&As[(wr * 64 + m * 16 + lr) * 32 + ls * 8];
#pragma unroll
        for (int n = 0; n < 4; n++)
            bfr[n] = *(const bf16x8*)&Bs[(wc * 64 + n * 16 + lr) * 32 + ls * 8];
#pragma unroll
        for (int m = 0; m < 4; m++)
#pragma unroll
            for (int n = 0; n < 4; n++)
                acc[m][n] = mfma16(af[m], bfr[n], acc[m][n]);
    }

    float bv[4];
#pragma unroll
    for (int n = 0; n < 4; n++) bv[n] = bias[n0 + wc * 64 + n * 16 + lr];
#pragma unroll
    for (int m = 0; m < 4; m++)
#pragma unroll
        for (int n = 0; n < 4; n++)
#pragma unroll
            for (int j = 0; j < 4; j++) {
                const size_t row = m0 + wr * 64 + m * 16 + ls * 4 + j;
                const size_t col = n0 + wc * 64 + n * 16 + lr;
                const float v = acc[m][n][j] + bv[n];
                if (BF16OUT) ((bf16_t*)Cv)[row * N + col] = f2b(v);
                else         ((float*)Cv)[row * N + col] = v;
            }
}

// ---------------- 256x192 pipelined 8-phase GEMM (QKV) ---------------------
// BK=64, 8 waves (2M x 4N, per-wave 128x48), 112 KiB LDS double-buffered.
// Register-pipelined: A-frags for phase q+1 issued in window q; MFMA(q) runs
// while those reads drain (compiler emits partial lgkmcnt, in-order DS).
__device__ __forceinline__ void st512(bf16_t* lds, const bf16_t* g,
                                      int K, int part, int tid) {
    const int idx = part * 512 + tid;
    const int row = idx >> 3, slot = idx & 7;
    async16(lds + idx * 8, g + (size_t)row * K + ((slot ^ (row & 7)) << 3));
}

#define LDB(bb) do {                                                           \
    _Pragma("unroll")                                                          \
    for (int n = 0; n < 3; n++)                                                \
        _Pragma("unroll")                                                      \
        for (int ks = 0; ks < 2; ks++) {                                       \
            const int r = wn * 48 + n * 16 + lr;                               \
            bfr[n][ks] = *(const bf16x8*)                                      \
                &(bb)[r * 64 + (((ks * 4 + ls) ^ (r & 7)) << 3)];              \
        }                                                                      \
} while (0)

#define LDA(dst, ab, q) do {                                                   \
    _Pragma("unroll")                                                          \
    for (int m = 0; m < 2; m++)                                                \
        _Pragma("unroll")                                                      \
        for (int ks = 0; ks < 2; ks++) {                                       \
            const int r = wm * 128 + (q) * 32 + m * 16 + lr;                   \
            dst[m][ks] = *(const bf16x8*)                                      \
                &(ab)[r * 64 + (((ks * 4 + ls) ^ (r & 7)) << 3)];              \
        }                                                                      \
} while (0)

#define MMA(q, src) do {                                                       \
    __builtin_amdgcn_sched_barrier(0);                                         \
    __builtin_amdgcn_s_setprio(1);                                             \
    _Pragma("unroll")                                                          \
    for (int ks = 0; ks < 2; ks++)                                             \
        _Pragma("unroll")                                                      \
        for (int n = 0; n < 3; n++)                                            \
            _Pragma("unroll")                                                  \
            for (int m = 0; m < 2; m++)                                        \
                acc[(q) * 2 + m][n] =                                          \
                    mfma16(src[m][ks], bfr[n][ks], acc[(q) * 2 + m][n]);       \
    __builtin_amdgcn_s_setprio(0);                                             \
    __builtin_amdgcn_sched_barrier(0);                                         \
} while (0)

// One K-tile = 4 phases; frag ping-pong afP/afQ issued one phase ahead.
#define KTILE3(ab, bb, I0, I1, I2, I3, TAILW) do {                             \
    LDB(bb);                                                                   \
    LDA(afP, ab, 0);                                                           \
    LDA(afQ, ab, 1);                                                           \
    I0; BAR();                                                                 \
    MMA(0, afP); BAR();                                                        \
    LDA(afP, ab, 2);                                                           \
    I1; BAR();                                                                 \
    MMA(1, afQ); BAR();                                                        \
    LDA(afQ, ab, 3);                                                           \
    I2; BAR();                                                                 \
    MMA(2, afP); BAR();                                                        \
    I3; BAR();                                                                 \
    MMA(3, afQ); TAILW; BAR();                                                 \
} while (0)

__global__ __launch_bounds__(512, 2) void gemm256x192(const bf16_t* __restrict__ A,
                                                      const bf16_t* __restrict__ BT,
                                                      const float* __restrict__ bias,
                                                      bf16_t* __restrict__ C,
                                                      int M, int N, int K) {
    __shared__ __align__(16) bf16_t As[2][256 * 64];
    __shared__ __align__(16) bf16_t Bs[2][192 * 64];

    const int nwg = (int)(gridDim.x * gridDim.y);
    const int id  = (int)(blockIdx.y * gridDim.x + blockIdx.x);
    const int wg  = (id & 7) * (nwg >> 3) + (id >> 3);      // XCD-bijective
    const int bx  = wg % (int)gridDim.x, by = wg / (int)gridDim.x;

    const int tid = threadIdx.x;
    const int wid = tid >> 6, lane = tid & 63;
    const int lr = lane & 15, ls = lane >> 4;
    const int wm = wid >> 2, wn = wid & 3;
    const size_t m0 = (size_t)by * 256, n0 = (size_t)bx * 192;

    const bf16_t* Ab = A + m0 * K;
    const bf16_t* Bb = BT + n0 * K;

    f32x4 acc[8][3];
#pragma unroll
    for (int m = 0; m < 8; m++)
#pragma unroll
        for (int n = 0; n < 3; n++) acc[m][n] = (f32x4){0.f, 0.f, 0.f, 0.f};
    bf16x8 bfr[3][2];
    bf16x8 afP[2][2], afQ[2][2];

    // prologue: A0(4) B0(3) B1(3); vmcnt(3) leaves B1 in flight
#pragma unroll
    for (int p = 0; p < 4; p++) st512(As[0], Ab, K, p, tid);
#pragma unroll
    for (int p = 0; p < 3; p++) st512(Bs[0], Bb, K, p, tid);
#pragma unroll
    for (int p = 0; p < 3; p++) st512(Bs[1], Bb + 64, K, p, tid);
    WAIT_VM3();
    BAR();

    const int ni = (K >> 6) >> 1;
#pragma unroll 1
    for (int i = 0; i < ni - 1; ++i) {
        const size_t t1 = (size_t)(2 * i + 1) * 64;
        const size_t t2 = (size_t)(2 * i + 2) * 64;
        const size_t t3 = (size_t)(2 * i + 3) * 64;
        KTILE3(As[0], Bs[0],
               { st512(As[1], Ab + t1, K, 0, tid); st512(As[1], Ab + t1, K, 1, tid); },
               { st512(As[1], Ab + t1, K, 2, tid); st512(As[1], Ab + t1, K, 3, tid); },
               { st512(Bs[0], Bb + t2, K, 0, tid); st512(Bs[0], Bb + t2, K, 1, tid); },
               { st512(Bs[0], Bb + t2, K, 2, tid); },
               WAIT_VM3());
        KTILE3(As[1], Bs[1],
               { st512(As[0], Ab + t2, K, 0, tid); st512(As[0], Ab + t2, K, 1, tid); },
               { st512(As[0], Ab + t2, K, 2, tid); st512(As[0], Ab + t2, K, 3, tid); },
               { st512(Bs[1], Bb + t3, K, 0, tid); st512(Bs[1], Bb + t3, K, 1, tid); },
               { st512(Bs[1], Bb + t3, K, 2, tid); },
               WAIT_VM3());
    }
    {   // tail iteration
        const size_t t1 = (size_t)(K - 64);
        KTILE3(As[0], Bs[0],
               { st512(As[1], Ab + t1, K, 0, tid); st512(As[1], Ab + t1, K, 1, tid); },
               { st512(As[1], Ab + t1, K, 2, tid); st512(As[1], Ab + t1, K, 3, tid); },
               { }, { },
               WAIT_VM0());
        KTILE3(As[1], Bs[1], { }, { }, { }, { }, );
    }

    float bv[3];
#pragma unroll
    for (int n = 0; n < 3; n++) bv[n] = bias[n0 + wn * 48 + n * 16 + lr];
#pragma unroll
    for (int mm = 0; mm < 8; mm++)
#pragma unroll
        for (int n = 0; n < 3; n++)
#pragma unroll
            for (int j = 0; j < 4; j++) {
                const size_t row = m0 + wm * 128 + mm * 16 + ls * 4 + j;
                const size_t col = n0 + wn * 48 + n * 16 + lr;
                C[row * N + col] = f2b(acc[mm][n][j] + bv[n]);
            }
}

// ---------------- RoPE on Q,K only (pow-2 indexing) ----------------
__global__ __launch_bounds__(256) void rope_qk(const bf16_t* __restrict__ qkv,
                                               const int* __restrict__ pos_ids,
                                               bf16_t* __restrict__ Qo,
                                               bf16_t* __restrict__ Ko) {
    const size_t gid = (size_t)blockIdx.x * 256 + threadIdx.x;
    const int d8 = (int)(gid & 15);
    const size_t t1 = gid >> 4;
    const int which = (int)(t1 & 1);
    const size_t t2 = t1 >> 1;
    const int nh = (int)(t2 & 15);
    const size_t bs = t2 >> 4;                  // b*S + s
    const int s = (int)(bs & (S_ - 1));
    const int b = (int)(bs >> 11);

    const bf16_t* src = qkv + bs * (3 * H_) + nh * 384 + which * 128 + d8 * 8;
    bf16x8 xv = *(const bf16x8*)src;
    const bf16_t* xu = (const bf16_t*)&xv;

    float xf[8];
#pragma unroll
    for (int i = 0; i < 8; i++) xf[i] = b2f(xu[i]);
    const int d0 = d8 * 8;
    if (d0 < 32) {                              // rotary on first 32 dims
        const float pos = (float)pos_ids[bs];
        bf16x8 yv = *(const bf16x8*)(src + ((d0 < 16) ? 16 : -16));
        const bf16_t* yu = (const bf16_t*)&yv;
#pragma unroll
        for (int i = 0; i < 8; i++) {
            const int d = d0 + i;
            const float th = pos * exp2f(-(float)(d & 15) * L2B16);
            const float c = cosf(th), sn = sinf(th);
            const float rot = (d < 16) ? -b2f(yu[i]) : b2f(yu[i]);
            xf[i] = xf[i] * c + rot * sn;
        }
    }
    bf16_t ou[8];
#pragma unroll
    for (int i = 0; i < 8; i++) ou[i] = f2b(xf[i]);
    bf16_t* dst = ((which == 0) ? Qo : Ko) + ((size_t)(b * NH_ + nh) * S_ + s) * HS_ + d0;
    *(bf16x8*)dst = *(const bf16x8*)ou;
}

// ---------------- V transpose: (b,s,h,d) -> (bh, d, s), LDS-tiled ----------
__global__ __launch_bounds__(256) void vxpose(const bf16_t* __restrict__ qkv,
                                              bf16_t* __restrict__ Vt) {
    __shared__ bf16_t t[128][130];
    const int bh = (int)blockIdx.x >> 4;
    const int s0 = ((int)blockIdx.x & 15) << 7;
    const int b = bh >> 4, h = bh & 15;
    const int tid = threadIdx.x;

    const int dc = tid & 15, sl = tid >> 4;     // sl 0..15
    const bf16_t* src = qkv + ((size_t)b * S_ + s0) * (3 * H_) + h * 384 + 256 + dc * 8;
#pragma unroll
    for (int c = 0; c < 8; c++) {
        const int s = sl + c * 16;
        bf16x8 v = *(const bf16x8*)(src + (size_t)s * (3 * H_));
        *(bf16x8*)&t[s][dc * 8] = v;
    }
    __syncthreads();
    const int sc = tid & 15, dl = tid >> 4;     // dl 0..15
    bf16_t* dst = Vt + ((size_t)bh * HS_) * S_ + s0 + sc * 8;
#pragma unroll
    for (int c = 0; c < 8; c++) {
        const int d = dl + c * 16;
        bf16_t o[8];
#pragma unroll
        for (int i = 0; i < 8; i++) o[i] = t[sc * 8 + i][d];
        *(bf16x8*)(dst + (size_t)d * S_) = *(const bf16x8*)o;
    }
}

// ---------------- causal flash attention (dbuf K/V, counted vmcnt) ----------
__device__ __forceinline__ void attn_stage(bf16_t* Kd, bf16_t* Vd,
                                           const bf16_t* Kg, const bf16_t* Vg,
                                           int kv0, int wid, int lane) {
#pragma unroll
    for (int jj = 0; jj < 4; jj++) {
        const int c = (wid << 2) + jj;
        const int rk = (c << 2) + (lane >> 4);        // K row 0..63
        async16(Kd + c * 512,
                Kg + (size_t)(kv0 + rk) * HS_ + (((lane & 15) ^ (rk & 7)) << 3));
        const int rv = (c << 3) + (lane >> 3);        // V^T row 0..127
        async16(Vd + c * 512,
                Vg + (size_t)rv * S_ + kv0 + (((lane & 7) ^ (rv & 7)) << 3));
    }
}

__global__ __launch_bounds__(256) void attn_fwd(const bf16_t* __restrict__ Q,
                                                const bf16_t* __restrict__ Kv,
                                                const bf16_t* __restrict__ Vt,
                                                const float* __restrict__ amask,
                                                bf16_t* __restrict__ ctx) {
    __shared__ __align__(16) bf16_t Ks[2][64 * 128];
    __shared__ __align__(16) bf16_t Vs[2][128 * 64];
    __shared__ __align__(16) bf16_t Ps[4][16 * 72];

    const int id = (int)(blockIdx.x + (blockIdx.y << 4));     // 0..511
    const int wg = ((id & 7) << 6) + (id >> 3);               // XCD-bijective
    const int pair = wg & 15;
    const int bh = wg >> 4;
    const int b = bh >> 4, h = bh & 15;
    const int tid = threadIdx.x, wid = tid >> 6, lane = tid & 63;
    const int lr = lane & 15, ls = lane >> 4;
    const float* am = amask + (size_t)b * S_;
    const bf16_t* Kg = Kv + (size_t)bh * S_ * HS_;
    const bf16_t* Vg = Vt + (size_t)bh * HS_ * S_;

#pragma unroll 1
    for (int half = 0; half < 2; ++half) {
        const int qt = half ? pair : (31 - pair);
        const int q0 = qt << 6;

        bf16x8 qf[4];
        const bf16_t* qp = Q + ((size_t)bh * S_ + q0 + wid * 16 + lr) * HS_;
#pragma unroll
        for (int dk = 0; dk < 4; dk++) qf[dk] = *(const bf16x8*)(qp + dk * 32 + ls * 8);

        float mrun[4], lrun[4];
        f32x4 oacc[8];
#pragma unroll
        for (int j = 0; j < 4; j++) { mrun[j] = -3.0e38f; lrun[j] = 0.f; }
#pragma unroll
        for (int dt = 0; dt < 8; dt++) oacc[dt] = (f32x4){0.f, 0.f, 0.f, 0.f};

        const int qrb = q0 + wid * 16 + ls * 4;

        attn_stage(Ks[0], Vs[0], Kg, Vg, 0, wid, lane);

#pragma unroll 1
        for (int step = 0; step <= qt; ++step) {
            const int cur = step & 1;
            const int kv0 = step << 6;
            if (step < qt) {
                attn_stage(Ks[cur ^ 1], Vs[cur ^ 1], Kg, Vg, (step + 1) << 6, wid, lane);
                WAIT_VM8();
            } else {
                WAIT_VM0();
            }
            BAR();

            f32x4 sacc[4];
#pragma unroll
            for (int t = 0; t < 4; t++) sacc[t] = (f32x4){0.f, 0.f, 0.f, 0.f};
#pragma unroll
            for (int t = 0; t < 4; t++)
#pragma unroll
                for (int dk = 0; dk < 4; dk++) {
                    const int row = t * 16 + lr;
                    bf16x8 kf = *(const bf16x8*)
                        &Ks[cur][row * 128 + (((dk * 4 + ls) ^ (row & 7)) << 3)];
                    sacc[t] = mfma16(qf[dk], kf, sacc[t]);
                }

            const bool diag = (step == qt);
            float sv[4][4], rmax[4];
#pragma unroll
            for (int j = 0; j < 4; j++) {
#pragma unroll
                for (int t = 0; t < 4; t++) {
                    const int kvp = kv0 + t * 16 + lr;
                    float v = sacc[t][j] * NORM_ + am[kvp];
                    if (diag && kvp > qrb + j) v = -3.0e38f;
                    sv[t][j] = v;
                }
                rmax[j] = fmaxf(fmaxf(sv[0][j], sv[1][j]), fmaxf(sv[2][j], sv[3][j]));
            }
#pragma unroll
            for (int off = 1; off < 16; off <<= 1)
#pragma unroll
                for (int j = 0; j < 4; j++)
                    rmax[j] = fmaxf(rmax[j], __shfl_xor(rmax[j], off));

            float scj[4], psum[4];
#pragma unroll
            for (int j = 0; j < 4; j++) {
                const float mnew = fmaxf(mrun[j], rmax[j]);
                scj[j] = __expf(mrun[j] - mnew);
                mrun[j] = mnew;
                psum[j] = 0.f;
#pragma unroll
                for (int t = 0; t < 4; t++) {
                    const float p = __expf(sv[t][j] - mnew);
                    psum[j] += p;
                    Ps[wid][(ls * 4 + j) * 72 + t * 16 + lr] = f2b(p);
                }
            }
#pragma unroll
            for (int off = 1; off < 16; off <<= 1)
#pragma unroll
                for (int j = 0; j < 4; j++) psum[j] += __shfl_xor(psum[j], off);
#pragma unroll
            for (int j = 0; j < 4; j++) {
                lrun[j] = lrun[j] * scj[j] + psum[j];
#pragma unroll
                for (int dt = 0; dt < 8; dt++) oacc[dt][j] *= scj[j];
            }

            bf16x8 pf[2];
#pragma unroll
            for (int hh = 0; hh < 2; hh++)
                pf[hh] = *(const bf16x8*)&Ps[wid][lr * 72 + hh * 32 + ls * 8];
#pragma unroll
            for (int dt = 0; dt < 8; dt++)
#pragma unroll
                for (int hh = 0; hh < 2; hh++) {
                    const int vrow = dt * 16 + lr;
                    bf16x8 vf = *(const bf16x8*)
                        &Vs[cur][vrow * 64 + (((hh * 4 + ls) ^ (vrow & 7)) << 3)];
                    oacc[dt] = mfma16(pf[hh], vf, oacc[dt]);
                }
            BAR();
        }

#pragma unroll
        for (int j = 0; j < 4; j++) {
            const float inv = 1.0f / lrun[j];
            bf16_t* dst = ctx + ((size_t)b * S_ + q0 + wid * 16 + ls * 4 + j) * H_ + h * HS_;
#pragma unroll
            for (int dt = 0; dt < 8; dt++) dst[dt * 16 + lr] = f2b(oacc[dt][j] * inv);
        }
    }
}

extern "C" void kernel_launch(void* const* d_in, const int* in_sizes, int n_in,
                              void* d_out, int out_size, void* d_ws, size_t ws_size,
                              hipStream_t stream) {
    const float* hs   = (const float*)d_in[0];
    const float* am   = (const float*)d_in[1];
    const int*   pos  = (const int*)d_in[2];
    const float* Wqkv = (const float*)d_in[3];
    const float* bqkv = (const float*)d_in[4];
    const float* Wd   = (const float*)d_in[5];
    const float* bd   = (const float*)d_in[6];
    float* out = (float*)d_out;
    char*  ws  = (char*)d_ws;

    const size_t MB = 1024 * 1024;
    bf16_t* X    = (bf16_t*)(ws);              // 16 MB (reused as ctx)
    bf16_t* WqT  = (bf16_t*)(ws + 16 * MB);    // 24 MB
    bf16_t* WdT  = (bf16_t*)(ws + 40 * MB);    // 8 MB
    bf16_t* QKVb = (bf16_t*)(ws + 48 * MB);    // 48 MB
    bf16_t* Qb   = (bf16_t*)(ws + 96 * MB);    // 16 MB
    bf16_t* Kb   = (bf16_t*)(ws + 112 * MB);   // 16 MB
    bf16_t* Vtb  = (bf16_t*)(ws + 128 * MB);   // 16 MB
    bf16_t* ctx  = X;

    cvt_bf16<<<4096, 256, 0, stream>>>(hs, X);
    transpose_cvt<<<dim3(6144 / 32, 2048 / 32), 256, 0, stream>>>(Wqkv, WqT, 2048, 6144);
    transpose_cvt<<<dim3(2048 / 32, 2048 / 32), 256, 0, stream>>>(Wd, WdT, 2048, 2048);
    gemm256x192<<<dim3(32, 16), 512, 0, stream>>>(X, WqT, bqkv, QKVb, 4096, 6144, 2048);
    rope_qk<<<8192, 256, 0, stream>>>(QKVb, pos, Qb, Kb);
    vxpose<<<512, 256, 0, stream>>>(QKVb, Vtb);
    attn_fwd<<<dim3(16, 32), 256, 0, stream>>>(Qb, Kb, Vtb, am, ctx);
    gemm_bias<0><<<dim3(2048 / 128, 4096 / 128), 256, 0, stream>>>(ctx, WdT, bd, out,
                                                                   4096, 2048, 2048);
}

// Round 6
// 330.312 us; speedup vs baseline: 1.1355x; 1.0203x over previous
//
#include <hip/hip_runtime.h>

#define B_   2
#define S_   2048
#define H_   2048
#define NH_  16
#define HS_  128
#define NORM_ 0.08838834764831845f          // 128^-0.5
#define L2B16 0.8304820237218407f           // log2(10000)/16

typedef unsigned short bf16_t;
typedef __bf16 bf16x8 __attribute__((ext_vector_type(8)));
typedef float  f32x4  __attribute__((ext_vector_type(4)));

__device__ __forceinline__ float b2f(bf16_t u) {
    return __uint_as_float(((unsigned int)u) << 16);
}
__device__ __forceinline__ bf16_t f2b(float f) {
    unsigned int x = __float_as_uint(f);
    x += 0x7fffu + ((x >> 16) & 1u);        // round-to-nearest-even
    return (bf16_t)(x >> 16);
}

__device__ __forceinline__ void async16(bf16_t* lds, const bf16_t* g) {
    __builtin_amdgcn_global_load_lds(
        (const __attribute__((address_space(1))) void*)g,
        (__attribute__((address_space(3))) void*)lds, 16, 0, 0);
}

__device__ __forceinline__ f32x4 mfma16(bf16x8 a, bf16x8 b, f32x4 c) {
    return __builtin_amdgcn_mfma_f32_16x16x32_bf16(a, b, c, 0, 0, 0);
}

#define BAR()        asm volatile("s_barrier" ::: "memory")
#define WAIT_VM0()   asm volatile("s_waitcnt vmcnt(0)" ::: "memory")
#define WAIT_VM8()   asm volatile("s_waitcnt vmcnt(8)" ::: "memory")

// ---------------- f32 -> bf16 convert (8 elems/thread) ----------------
__global__ __launch_bounds__(256) void cvt_bf16(const float* __restrict__ in,
                                                bf16_t* __restrict__ out) {
    const size_t i = (size_t)blockIdx.x * 256 + threadIdx.x;
    const float4* p = (const float4*)in + i * 2;
    float4 a = p[0], b = p[1];
    bf16_t o[8] = { f2b(a.x), f2b(a.y), f2b(a.z), f2b(a.w),
                    f2b(b.x), f2b(b.y), f2b(b.z), f2b(b.w) };
    *((bf16x8*)out + i) = *(const bf16x8*)o;
}

// ---------------- W (KxN f32) -> W^T (NxK bf16), 32x32 tiles ----------------
__global__ __launch_bounds__(256) void transpose_cvt(const float* __restrict__ W,
                                                     bf16_t* __restrict__ WT,
                                                     int K, int N) {
    __shared__ float tile[32][33];
    const int tx = threadIdx.x & 31, ty = threadIdx.x >> 5;
    const int n0 = blockIdx.x * 32, k0 = blockIdx.y * 32;
#pragma unroll
    for (int i = 0; i < 4; i++)
        tile[ty + i * 8][tx] = W[(size_t)(k0 + ty + i * 8) * N + n0 + tx];
    __syncthreads();
#pragma unroll
    for (int i = 0; i < 4; i++)
        WT[(size_t)(n0 + ty + i * 8) * K + k0 + tx] = f2b(tile[tx][ty + i * 8]);
}

// ---------------- 128x128 2-phase GEMM (proven; used for dense) ------------
template <int BF16OUT>
__global__ __launch_bounds__(256) void gemm_bias(const bf16_t* __restrict__ A,
                                                 const bf16_t* __restrict__ BT,
                                                 const float* __restrict__ bias,
                                                 void* __restrict__ Cv,
                                                 int M, int N, int K) {
    __shared__ __align__(16) bf16_t As[128 * 32];
    __shared__ __align__(16) bf16_t Bs[128 * 32];
    const int tid = threadIdx.x;
    const int wid = tid >> 6, lane = tid & 63;
    const int lr = lane & 15, ls = lane >> 4;
    const int wr = wid >> 1, wc = wid & 1;
    const size_t m0 = (size_t)blockIdx.y * 128, n0 = (size_t)blockIdx.x * 128;

    f32x4 acc[4][4];
#pragma unroll
    for (int m = 0; m < 4; m++)
#pragma unroll
        for (int n = 0; n < 4; n++) acc[m][n] = (f32x4){0.f, 0.f, 0.f, 0.f};

    const int srow = lane >> 2, sk = (lane & 3) * 8;

    for (int k0 = 0; k0 < K; k0 += 32) {
        __syncthreads();
#pragma unroll
        for (int j = 0; j < 2; j++) {
            const int rr = (wid * 2 + j) * 16 + srow;
            async16(As + (wid * 2 + j) * 512, A + (m0 + rr) * K + k0 + sk);
            async16(Bs + (wid * 2 + j) * 512, BT + (n0 + rr) * K + k0 + sk);
        }
        __syncthreads();
        bf16x8 af[4], bfr[4];
#pragma unroll
        for (int m = 0; m < 4; m++)
            af[m] = *(const bf16x8*)&As[(wr * 64 + m * 16 + lr) * 32 + ls * 8];
#pragma unroll
        for (int n = 0; n < 4; n++)
            bfr[n] = *(const bf16x8*)&Bs[(wc * 64 + n * 16 + lr) * 32 + ls * 8];
#pragma unroll
        for (int m = 0; m < 4; m++)
#pragma unroll
            for (int n = 0; n < 4; n++)
                acc[m][n] = mfma16(af[m], bfr[n], acc[m][n]);
    }

    float bv[4];
#pragma unroll
    for (int n = 0; n < 4; n++) bv[n] = bias[n0 + wc * 64 + n * 16 + lr];
#pragma unroll
    for (int m = 0; m < 4; m++)
#pragma unroll
        for (int n = 0; n < 4; n++)
#pragma unroll
            for (int j = 0; j < 4; j++) {
                const size_t row = m0 + wr * 64 + m * 16 + ls * 4 + j;
                const size_t col = n0 + wc * 64 + n * 16 + lr;
                const float v = acc[m][n][j] + bv[n];
                if (BF16OUT) ((bf16_t*)Cv)[row * N + col] = f2b(v);
                else         ((float*)Cv)[row * N + col] = v;
            }
}

// ---------------- 256x192 single-barrier GEMM (QKV) ------------------------
// BK=64, 8 waves (2M x 4N, per-wave 128x48), 112 KiB LDS double-buffered.
// ONE barrier + vmcnt(0) per K-tile. Stages for tile t+1 issued at window
// start (full-tile slack >> HBM latency). Frag reads one phase ahead via
// explicit ping-pong; compiler's partial lgkmcnt overlaps reads with MFMA;
// 8 desynced waves overlap LDS service and matrix pipe at CU level.
__device__ __forceinline__ void st512(bf16_t* lds, const bf16_t* g,
                                      int K, int part, int tid) {
    const int idx = part * 512 + tid;
    const int row = idx >> 3, slot = idx & 7;
    async16(lds + idx * 8, g + (size_t)row * K + ((slot ^ (row & 7)) << 3));
}

#define LDB(bb) do {                                                           \
    _Pragma("unroll")                                                          \
    for (int n = 0; n < 3; n++)                                                \
        _Pragma("unroll")                                                      \
        for (int ks = 0; ks < 2; ks++) {                                       \
            const int r = wn * 48 + n * 16 + lr;                               \
            bfr[n][ks] = *(const bf16x8*)                                      \
                &(bb)[r * 64 + (((ks * 4 + ls) ^ (r & 7)) << 3)];              \
        }                                                                      \
} while (0)

#define LDA(dst, ab, q) do {                                                   \
    _Pragma("unroll")                                                          \
    for (int m = 0; m < 2; m++)                                                \
        _Pragma("unroll")                                                      \
        for (int ks = 0; ks < 2; ks++) {                                       \
            const int r = wm * 128 + (q) * 32 + m * 16 + lr;                   \
            dst[m][ks] = *(const bf16x8*)                                      \
                &(ab)[r * 64 + (((ks * 4 + ls) ^ (r & 7)) << 3)];              \
        }                                                                      \
} while (0)

#define MMA(q, src) do {                                                       \
    __builtin_amdgcn_s_setprio(1);                                             \
    _Pragma("unroll")                                                          \
    for (int ks = 0; ks < 2; ks++)                                             \
        _Pragma("unroll")                                                      \
        for (int n = 0; n < 3; n++)                                            \
            _Pragma("unroll")                                                  \
            for (int m = 0; m < 2; m++)                                        \
                acc[(q) * 2 + m][n] =                                          \
                    mfma16(src[m][ks], bfr[n][ks], acc[(q) * 2 + m][n]);       \
    __builtin_amdgcn_s_setprio(0);                                             \
} while (0)

__global__ __launch_bounds__(512, 2) void gemm_qkv(const bf16_t* __restrict__ A,
                                                   const bf16_t* __restrict__ BT,
                                                   const float* __restrict__ bias,
                                                   bf16_t* __restrict__ C,
                                                   int M, int N, int K) {
    __shared__ __align__(16) bf16_t As[2][256 * 64];
    __shared__ __align__(16) bf16_t Bs[2][192 * 64];

    const int nwg = (int)(gridDim.x * gridDim.y);
    const int id  = (int)(blockIdx.y * gridDim.x + blockIdx.x);
    const int wg  = (id & 7) * (nwg >> 3) + (id >> 3);      // XCD-bijective
    const int bx  = wg % (int)gridDim.x, by = wg / (int)gridDim.x;

    const int tid = threadIdx.x;
    const int wid = tid >> 6, lane = tid & 63;
    const int lr = lane & 15, ls = lane >> 4;
    const int wm = wid >> 2, wn = wid & 3;
    const size_t m0 = (size_t)by * 256, n0 = (size_t)bx * 192;

    const bf16_t* Ab = A + m0 * K;
    const bf16_t* Bb = BT + n0 * K;

    f32x4 acc[8][3];
#pragma unroll
    for (int m = 0; m < 8; m++)
#pragma unroll
        for (int n = 0; n < 3; n++) acc[m][n] = (f32x4){0.f, 0.f, 0.f, 0.f};
    bf16x8 bfr[3][2];
    bf16x8 afP[2][2], afQ[2][2];

    // prologue: stage tile 0
#pragma unroll
    for (int p = 0; p < 4; p++) st512(As[0], Ab, K, p, tid);
#pragma unroll
    for (int p = 0; p < 3; p++) st512(Bs[0], Bb, K, p, tid);
    WAIT_VM0();
    BAR();

    const int nt = K >> 6;
#pragma unroll 1
    for (int i = 0; i < nt; ++i) {
        const int c = i & 1;
        const bf16_t* Ac = As[c];
        const bf16_t* Bc = Bs[c];
        // stage tile i+1 into the other buffer, at window start
        if (i + 1 < nt) {
            const size_t ko = (size_t)(i + 1) * 64;
            bf16_t* Ad = As[c ^ 1];
            bf16_t* Bd = Bs[c ^ 1];
#pragma unroll
            for (int p = 0; p < 4; p++) st512(Ad, Ab + ko, K, p, tid);
#pragma unroll
            for (int p = 0; p < 3; p++) st512(Bd, Bb + ko, K, p, tid);
        }
        __builtin_amdgcn_sched_barrier(0);     // pin stage issues early
        // frag reads one phase ahead; MFMAs overlap the in-flight reads
        LDA(afP, Ac, 0);
        LDB(Bc);
        LDA(afQ, Ac, 1);
        MMA(0, afP);
        LDA(afP, Ac, 2);
        MMA(1, afQ);
        LDA(afQ, Ac, 3);
        MMA(2, afP);
        MMA(3, afQ);
        WAIT_VM0();
        BAR();
    }

    float bv[3];
#pragma unroll
    for (int n = 0; n < 3; n++) bv[n] = bias[n0 + wn * 48 + n * 16 + lr];
#pragma unroll
    for (int mm = 0; mm < 8; mm++)
#pragma unroll
        for (int n = 0; n < 3; n++)
#pragma unroll
            for (int j = 0; j < 4; j++) {
                const size_t row = m0 + wm * 128 + mm * 16 + ls * 4 + j;
                const size_t col = n0 + wn * 48 + n * 16 + lr;
                C[row * N + col] = f2b(acc[mm][n][j] + bv[n]);
            }
}

// ---------------- RoPE on Q,K only (pow-2 indexing) ----------------
__global__ __launch_bounds__(256) void rope_qk(const bf16_t* __restrict__ qkv,
                                               const int* __restrict__ pos_ids,
                                               bf16_t* __restrict__ Qo,
                                               bf16_t* __restrict__ Ko) {
    const size_t gid = (size_t)blockIdx.x * 256 + threadIdx.x;
    const int d8 = (int)(gid & 15);
    const size_t t1 = gid >> 4;
    const int which = (int)(t1 & 1);
    const size_t t2 = t1 >> 1;
    const int nh = (int)(t2 & 15);
    const size_t bs = t2 >> 4;                  // b*S + s
    const int s = (int)(bs & (S_ - 1));
    const int b = (int)(bs >> 11);

    const bf16_t* src = qkv + bs * (3 * H_) + nh * 384 + which * 128 + d8 * 8;
    bf16x8 xv = *(const bf16x8*)src;
    const bf16_t* xu = (const bf16_t*)&xv;

    float xf[8];
#pragma unroll
    for (int i = 0; i < 8; i++) xf[i] = b2f(xu[i]);
    const int d0 = d8 * 8;
    if (d0 < 32) {                              // rotary on first 32 dims
        const float pos = (float)pos_ids[bs];
        bf16x8 yv = *(const bf16x8*)(src + ((d0 < 16) ? 16 : -16));
        const bf16_t* yu = (const bf16_t*)&yv;
#pragma unroll
        for (int i = 0; i < 8; i++) {
            const int d = d0 + i;
            const float th = pos * exp2f(-(float)(d & 15) * L2B16);
            const float c = cosf(th), sn = sinf(th);
            const float rot = (d < 16) ? -b2f(yu[i]) : b2f(yu[i]);
            xf[i] = xf[i] * c + rot * sn;
        }
    }
    bf16_t ou[8];
#pragma unroll
    for (int i = 0; i < 8; i++) ou[i] = f2b(xf[i]);
    bf16_t* dst = ((which == 0) ? Qo : Ko) + ((size_t)(b * NH_ + nh) * S_ + s) * HS_ + d0;
    *(bf16x8*)dst = *(const bf16x8*)ou;
}

// ---------------- V transpose: (b,s,h,d) -> (bh, d, s), LDS-tiled ----------
__global__ __launch_bounds__(256) void vxpose(const bf16_t* __restrict__ qkv,
                                              bf16_t* __restrict__ Vt) {
    __shared__ bf16_t t[128][130];
    const int bh = (int)blockIdx.x >> 4;
    const int s0 = ((int)blockIdx.x & 15) << 7;
    const int b = bh >> 4, h = bh & 15;
    const int tid = threadIdx.x;

    const int dc = tid & 15, sl = tid >> 4;     // sl 0..15
    const bf16_t* src = qkv + ((size_t)b * S_ + s0) * (3 * H_) + h * 384 + 256 + dc * 8;
#pragma unroll
    for (int c = 0; c < 8; c++) {
        const int s = sl + c * 16;
        bf16x8 v = *(const bf16x8*)(src + (size_t)s * (3 * H_));
        *(bf16x8*)&t[s][dc * 8] = v;
    }
    __syncthreads();
    const int sc = tid & 15, dl = tid >> 4;     // dl 0..15
    bf16_t* dst = Vt + ((size_t)bh * HS_) * S_ + s0 + sc * 8;
#pragma unroll
    for (int c = 0; c < 8; c++) {
        const int d = dl + c * 16;
        bf16_t o[8];
#pragma unroll
        for (int i = 0; i < 8; i++) o[i] = t[sc * 8 + i][d];
        *(bf16x8*)(dst + (size_t)d * S_) = *(const bf16x8*)o;
    }
}

// ---------------- causal flash attention (dbuf K/V, counted vmcnt) ----------
__device__ __forceinline__ void attn_stage(bf16_t* Kd, bf16_t* Vd,
                                           const bf16_t* Kg, const bf16_t* Vg,
                                           int kv0, int wid, int lane) {
#pragma unroll
    for (int jj = 0; jj < 4; jj++) {
        const int c = (wid << 2) + jj;
        const int rk = (c << 2) + (lane >> 4);        // K row 0..63
        async16(Kd + c * 512,
                Kg + (size_t)(kv0 + rk) * HS_ + (((lane & 15) ^ (rk & 7)) << 3));
        const int rv = (c << 3) + (lane >> 3);        // V^T row 0..127
        async16(Vd + c * 512,
                Vg + (size_t)rv * S_ + kv0 + (((lane & 7) ^ (rv & 7)) << 3));
    }
}

__global__ __launch_bounds__(256) void attn_fwd(const bf16_t* __restrict__ Q,
                                                const bf16_t* __restrict__ Kv,
                                                const bf16_t* __restrict__ Vt,
                                                const float* __restrict__ amask,
                                                bf16_t* __restrict__ ctx) {
    __shared__ __align__(16) bf16_t Ks[2][64 * 128];
    __shared__ __align__(16) bf16_t Vs[2][128 * 64];
    __shared__ __align__(16) bf16_t Ps[4][16 * 72];

    const int id = (int)(blockIdx.x + (blockIdx.y << 4));     // 0..511
    const int wg = ((id & 7) << 6) + (id >> 3);               // XCD-bijective
    const int pair = wg & 15;
    const int bh = wg >> 4;
    const int b = bh >> 4, h = bh & 15;
    const int tid = threadIdx.x, wid = tid >> 6, lane = tid & 63;
    const int lr = lane & 15, ls = lane >> 4;
    const float* am = amask + (size_t)b * S_;
    const bf16_t* Kg = Kv + (size_t)bh * S_ * HS_;
    const bf16_t* Vg = Vt + (size_t)bh * HS_ * S_;

#pragma unroll 1
    for (int half = 0; half < 2; ++half) {
        const int qt = half ? pair : (31 - pair);
        const int q0 = qt << 6;

        bf16x8 qf[4];
        const bf16_t* qp = Q + ((size_t)bh * S_ + q0 + wid * 16 + lr) * HS_;
#pragma unroll
        for (int dk = 0; dk < 4; dk++) qf[dk] = *(const bf16x8*)(qp + dk * 32 + ls * 8);

        float mrun[4], lrun[4];
        f32x4 oacc[8];
#pragma unroll
        for (int j = 0; j < 4; j++) { mrun[j] = -3.0e38f; lrun[j] = 0.f; }
#pragma unroll
        for (int dt = 0; dt < 8; dt++) oacc[dt] = (f32x4){0.f, 0.f, 0.f, 0.f};

        const int qrb = q0 + wid * 16 + ls * 4;

        attn_stage(Ks[0], Vs[0], Kg, Vg, 0, wid, lane);

#pragma unroll 1
        for (int step = 0; step <= qt; ++step) {
            const int cur = step & 1;
            const int kv0 = step << 6;
            if (step < qt) {
                attn_stage(Ks[cur ^ 1], Vs[cur ^ 1], Kg, Vg, (step + 1) << 6, wid, lane);
                WAIT_VM8();
            } else {
                WAIT_VM0();
            }
            BAR();

            f32x4 sacc[4];
#pragma unroll
            for (int t = 0; t < 4; t++) sacc[t] = (f32x4){0.f, 0.f, 0.f, 0.f};
#pragma unroll
            for (int t = 0; t < 4; t++)
#pragma unroll
                for (int dk = 0; dk < 4; dk++) {
                    const int row = t * 16 + lr;
                    bf16x8 kf = *(const bf16x8*)
                        &Ks[cur][row * 128 + (((dk * 4 + ls) ^ (row & 7)) << 3)];
                    sacc[t] = mfma16(qf[dk], kf, sacc[t]);
                }

            const bool diag = (step == qt);
            float sv[4][4], rmax[4];
#pragma unroll
            for (int j = 0; j < 4; j++) {
#pragma unroll
                for (int t = 0; t < 4; t++) {
                    const int kvp = kv0 + t * 16 + lr;
                    float v = sacc[t][j] * NORM_ + am[kvp];
                    if (diag && kvp > qrb + j) v = -3.0e38f;
                    sv[t][j] = v;
                }
                rmax[j] = fmaxf(fmaxf(sv[0][j], sv[1][j]), fmaxf(sv[2][j], sv[3][j]));
            }
#pragma unroll
            for (int off = 1; off < 16; off <<= 1)
#pragma unroll
                for (int j = 0; j < 4; j++)
                    rmax[j] = fmaxf(rmax[j], __shfl_xor(rmax[j], off));

            float scj[4], psum[4];
#pragma unroll
            for (int j = 0; j < 4; j++) {
                const float mnew = fmaxf(mrun[j], rmax[j]);
                scj[j] = __expf(mrun[j] - mnew);
                mrun[j] = mnew;
                psum[j] = 0.f;
#pragma unroll
                for (int t = 0; t < 4; t++) {
                    const float p = __expf(sv[t][j] - mnew);
                    psum[j] += p;
                    Ps[wid][(ls * 4 + j) * 72 + t * 16 + lr] = f2b(p);
                }
            }
#pragma unroll
            for (int off = 1; off < 16; off <<= 1)
#pragma unroll
                for (int j = 0; j < 4; j++) psum[j] += __shfl_xor(psum[j], off);
#pragma unroll
            for (int j = 0; j < 4; j++) {
                lrun[j] = lrun[j] * scj[j] + psum[j];
#pragma unroll
                for (int dt = 0; dt < 8; dt++) oacc[dt][j] *= scj[j];
            }

            bf16x8 pf[2];
#pragma unroll
            for (int hh = 0; hh < 2; hh++)
                pf[hh] = *(const bf16x8*)&Ps[wid][lr * 72 + hh * 32 + ls * 8];
#pragma unroll
            for (int dt = 0; dt < 8; dt++)
#pragma unroll
                for (int hh = 0; hh < 2; hh++) {
                    const int vrow = dt * 16 + lr;
                    bf16x8 vf = *(const bf16x8*)
                        &Vs[cur][vrow * 64 + (((hh * 4 + ls) ^ (vrow & 7)) << 3)];
                    oacc[dt] = mfma16(pf[hh], vf, oacc[dt]);
                }
            BAR();
        }

#pragma unroll
        for (int j = 0; j < 4; j++) {
            const float inv = 1.0f / lrun[j];
            bf16_t* dst = ctx + ((size_t)b * S_ + q0 + wid * 16 + ls * 4 + j) * H_ + h * HS_;
#pragma unroll
            for (int dt = 0; dt < 8; dt++) dst[dt * 16 + lr] = f2b(oacc[dt][j] * inv);
        }
    }
}

extern "C" void kernel_launch(void* const* d_in, const int* in_sizes, int n_in,
                              void* d_out, int out_size, void* d_ws, size_t ws_size,
                              hipStream_t stream) {
    const float* hs   = (const float*)d_in[0];
    const float* am   = (const float*)d_in[1];
    const int*   pos  = (const int*)d_in[2];
    const float* Wqkv = (const float*)d_in[3];
    const float* bqkv = (const float*)d_in[4];
    const float* Wd   = (const float*)d_in[5];
    const float* bd   = (const float*)d_in[6];
    float* out = (float*)d_out;
    char*  ws  = (char*)d_ws;

    const size_t MB = 1024 * 1024;
    bf16_t* X    = (bf16_t*)(ws);              // 16 MB (reused as ctx)
    bf16_t* WqT  = (bf16_t*)(ws + 16 * MB);    // 24 MB
    bf16_t* WdT  = (bf16_t*)(ws + 40 * MB);    // 8 MB
    bf16_t* QKVb = (bf16_t*)(ws + 48 * MB);    // 48 MB
    bf16_t* Qb   = (bf16_t*)(ws + 96 * MB);    // 16 MB
    bf16_t* Kb   = (bf16_t*)(ws + 112 * MB);   // 16 MB
    bf16_t* Vtb  = (bf16_t*)(ws + 128 * MB);   // 16 MB
    bf16_t* ctx  = X;

    cvt_bf16<<<4096, 256, 0, stream>>>(hs, X);
    transpose_cvt<<<dim3(6144 / 32, 2048 / 32), 256, 0, stream>>>(Wqkv, WqT, 2048, 6144);
    transpose_cvt<<<dim3(2048 / 32, 2048 / 32), 256, 0, stream>>>(Wd, WdT, 2048, 2048);
    gemm_qkv<<<dim3(32, 16), 512, 0, stream>>>(X, WqT, bqkv, QKVb, 4096, 6144, 2048);
    rope_qk<<<8192, 256, 0, stream>>>(QKVb, pos, Qb, Kb);
    vxpose<<<512, 256, 0, stream>>>(QKVb, Vtb);
    attn_fwd<<<dim3(16, 32), 256, 0, stream>>>(Qb, Kb, Vtb, am, ctx);
    gemm_bias<0><<<dim3(2048 / 128, 4096 / 128), 256, 0, stream>>>(ctx, WdT, bd, out,
                                                                   4096, 2048, 2048);
}

// Round 8
// 320.325 us; speedup vs baseline: 1.1709x; 1.0312x over previous
//
#include <hip/hip_runtime.h>

#define B_   2
#define S_   2048
#define H_   2048
#define NH_  16
#define HS_  128
#define NORM_ 0.08838834764831845f          // 128^-0.5
#define L2B16 0.8304820237218407f           // log2(10000)/16

typedef unsigned short bf16_t;
typedef __bf16 bf16x8 __attribute__((ext_vector_type(8)));
typedef float  f32x4  __attribute__((ext_vector_type(4)));

__device__ __forceinline__ float b2f(bf16_t u) {
    return __uint_as_float(((unsigned int)u) << 16);
}
__device__ __forceinline__ bf16_t f2b(float f) {
    unsigned int x = __float_as_uint(f);
    x += 0x7fffu + ((x >> 16) & 1u);        // round-to-nearest-even
    return (bf16_t)(x >> 16);
}

__device__ __forceinline__ void async16(bf16_t* lds, const bf16_t* g) {
    __builtin_amdgcn_global_load_lds(
        (const __attribute__((address_space(1))) void*)g,
        (__attribute__((address_space(3))) void*)lds, 16, 0, 0);
}

__device__ __forceinline__ f32x4 mfma16(bf16x8 a, bf16x8 b, f32x4 c) {
    return __builtin_amdgcn_mfma_f32_16x16x32_bf16(a, b, c, 0, 0, 0);
}

#define BAR()        asm volatile("s_barrier" ::: "memory")
#define WAIT_VM0()   asm volatile("s_waitcnt vmcnt(0)" ::: "memory")
#define WAIT_VM8()   asm volatile("s_waitcnt vmcnt(8)" ::: "memory")

// ---------------- f32 -> bf16 convert (8 elems/thread) ----------------
__global__ __launch_bounds__(256) void cvt_bf16(const float* __restrict__ in,
                                                bf16_t* __restrict__ out) {
    const size_t i = (size_t)blockIdx.x * 256 + threadIdx.x;
    const float4* p = (const float4*)in + i * 2;
    float4 a = p[0], b = p[1];
    bf16_t o[8] = { f2b(a.x), f2b(a.y), f2b(a.z), f2b(a.w),
                    f2b(b.x), f2b(b.y), f2b(b.z), f2b(b.w) };
    *((bf16x8*)out + i) = *(const bf16x8*)o;
}

// ---------------- W (KxN f32) -> W^T (NxK bf16), 32x32 tiles ----------------
__global__ __launch_bounds__(256) void transpose_cvt(const float* __restrict__ W,
                                                     bf16_t* __restrict__ WT,
                                                     int K, int N) {
    __shared__ float tile[32][33];
    const int tx = threadIdx.x & 31, ty = threadIdx.x >> 5;
    const int n0 = blockIdx.x * 32, k0 = blockIdx.y * 32;
#pragma unroll
    for (int i = 0; i < 4; i++)
        tile[ty + i * 8][tx] = W[(size_t)(k0 + ty + i * 8) * N + n0 + tx];
    __syncthreads();
#pragma unroll
    for (int i = 0; i < 4; i++)
        WT[(size_t)(n0 + ty + i * 8) * K + k0 + tx] = f2b(tile[tx][ty + i * 8]);
}

// ---------------- 128x128 2-phase GEMM (proven; used for dense) ------------
template <int BF16OUT>
__global__ __launch_bounds__(256) void gemm_bias(const bf16_t* __restrict__ A,
                                                 const bf16_t* __restrict__ BT,
                                                 const float* __restrict__ bias,
                                                 void* __restrict__ Cv,
                                                 int M, int N, int K) {
    __shared__ __align__(16) bf16_t As[128 * 32];
    __shared__ __align__(16) bf16_t Bs[128 * 32];
    const int tid = threadIdx.x;
    const int wid = tid >> 6, lane = tid & 63;
    const int lr = lane & 15, ls = lane >> 4;
    const int wr = wid >> 1, wc = wid & 1;
    const size_t m0 = (size_t)blockIdx.y * 128, n0 = (size_t)blockIdx.x * 128;

    f32x4 acc[4][4];
#pragma unroll
    for (int m = 0; m < 4; m++)
#pragma unroll
        for (int n = 0; n < 4; n++) acc[m][n] = (f32x4){0.f, 0.f, 0.f, 0.f};

    const int srow = lane >> 2, sk = (lane & 3) * 8;

    for (int k0 = 0; k0 < K; k0 += 32) {
        __syncthreads();
#pragma unroll
        for (int j = 0; j < 2; j++) {
            const int rr = (wid * 2 + j) * 16 + srow;
            async16(As + (wid * 2 + j) * 512, A + (m0 + rr) * K + k0 + sk);
            async16(Bs + (wid * 2 + j) * 512, BT + (n0 + rr) * K + k0 + sk);
        }
        __syncthreads();
        bf16x8 af[4], bfr[4];
#pragma unroll
        for (int m = 0; m < 4; m++)
            af[m] = *(const bf16x8*)&As[(wr * 64 + m * 16 + lr) * 32 + ls * 8];
#pragma unroll
        for (int n = 0; n < 4; n++)
            bfr[n] = *(const bf16x8*)&Bs[(wc * 64 + n * 16 + lr) * 32 + ls * 8];
#pragma unroll
        for (int m = 0; m < 4; m++)
#pragma unroll
            for (int n = 0; n < 4; n++)
                acc[m][n] = mfma16(af[m], bfr[n], acc[m][n]);
    }

    float bv[4];
#pragma unroll
    for (int n = 0; n < 4; n++) bv[n] = bias[n0 + wc * 64 + n * 16 + lr];
#pragma unroll
    for (int m = 0; m < 4; m++)
#pragma unroll
        for (int n = 0; n < 4; n++)
#pragma unroll
            for (int j = 0; j < 4; j++) {
                const size_t row = m0 + wr * 64 + m * 16 + ls * 4 + j;
                const size_t col = n0 + wc * 64 + n * 16 + lr;
                const float v = acc[m][n][j] + bv[n];
                if (BF16OUT) ((bf16_t*)Cv)[row * N + col] = f2b(v);
                else         ((float*)Cv)[row * N + col] = v;
            }
}

// ---------------- 256x192 single-barrier GEMM (QKV) ------------------------
__device__ __forceinline__ void st512(bf16_t* lds, const bf16_t* g,
                                      int K, int part, int tid) {
    const int idx = part * 512 + tid;
    const int row = idx >> 3, slot = idx & 7;
    async16(lds + idx * 8, g + (size_t)row * K + ((slot ^ (row & 7)) << 3));
}

#define LDB(bb) do {                                                           \
    _Pragma("unroll")                                                          \
    for (int n = 0; n < 3; n++)                                                \
        _Pragma("unroll")                                                      \
        for (int ks = 0; ks < 2; ks++) {                                       \
            const int r = wn * 48 + n * 16 + lr;                               \
            bfr[n][ks] = *(const bf16x8*)                                      \
                &(bb)[r * 64 + (((ks * 4 + ls) ^ (r & 7)) << 3)];              \
        }                                                                      \
} while (0)

#define LDA(dst, ab, q) do {                                                   \
    _Pragma("unroll")                                                          \
    for (int m = 0; m < 2; m++)                                                \
        _Pragma("unroll")                                                      \
        for (int ks = 0; ks < 2; ks++) {                                       \
            const int r = wm * 128 + (q) * 32 + m * 16 + lr;                   \
            dst[m][ks] = *(const bf16x8*)                                      \
                &(ab)[r * 64 + (((ks * 4 + ls) ^ (r & 7)) << 3)];              \
        }                                                                      \
} while (0)

#define MMA(q, src) do {                                                       \
    __builtin_amdgcn_s_setprio(1);                                             \
    _Pragma("unroll")                                                          \
    for (int ks = 0; ks < 2; ks++)                                             \
        _Pragma("unroll")                                                      \
        for (int n = 0; n < 3; n++)                                            \
            _Pragma("unroll")                                                  \
            for (int m = 0; m < 2; m++)                                        \
                acc[(q) * 2 + m][n] =                                          \
                    mfma16(src[m][ks], bfr[n][ks], acc[(q) * 2 + m][n]);       \
    __builtin_amdgcn_s_setprio(0);                                             \
} while (0)

__global__ __launch_bounds__(512, 2) void gemm_qkv(const bf16_t* __restrict__ A,
                                                   const bf16_t* __restrict__ BT,
                                                   const float* __restrict__ bias,
                                                   bf16_t* __restrict__ C,
                                                   int M, int N, int K) {
    __shared__ __align__(16) bf16_t As[2][256 * 64];
    __shared__ __align__(16) bf16_t Bs[2][192 * 64];

    const int nwg = (int)(gridDim.x * gridDim.y);
    const int id  = (int)(blockIdx.y * gridDim.x + blockIdx.x);
    const int wg  = (id & 7) * (nwg >> 3) + (id >> 3);      // XCD-bijective
    const int bx  = wg % (int)gridDim.x, by = wg / (int)gridDim.x;

    const int tid = threadIdx.x;
    const int wid = tid >> 6, lane = tid & 63;
    const int lr = lane & 15, ls = lane >> 4;
    const int wm = wid >> 2, wn = wid & 3;
    const size_t m0 = (size_t)by * 256, n0 = (size_t)bx * 192;

    const bf16_t* Ab = A + m0 * K;
    const bf16_t* Bb = BT + n0 * K;

    f32x4 acc[8][3];
#pragma unroll
    for (int m = 0; m < 8; m++)
#pragma unroll
        for (int n = 0; n < 3; n++) acc[m][n] = (f32x4){0.f, 0.f, 0.f, 0.f};
    bf16x8 bfr[3][2];
    bf16x8 afP[2][2], afQ[2][2];

    // prologue: stage tile 0
#pragma unroll
    for (int p = 0; p < 4; p++) st512(As[0], Ab, K, p, tid);
#pragma unroll
    for (int p = 0; p < 3; p++) st512(Bs[0], Bb, K, p, tid);
    WAIT_VM0();
    BAR();

    const int nt = K >> 6;
#pragma unroll 1
    for (int i = 0; i < nt; ++i) {
        const int c = i & 1;
        const bf16_t* Ac = As[c];
        const bf16_t* Bc = Bs[c];
        if (i + 1 < nt) {
            const size_t ko = (size_t)(i + 1) * 64;
            bf16_t* Ad = As[c ^ 1];
            bf16_t* Bd = Bs[c ^ 1];
#pragma unroll
            for (int p = 0; p < 4; p++) st512(Ad, Ab + ko, K, p, tid);
#pragma unroll
            for (int p = 0; p < 3; p++) st512(Bd, Bb + ko, K, p, tid);
        }
        __builtin_amdgcn_sched_barrier(0);     // pin stage issues early
        LDA(afP, Ac, 0);
        LDB(Bc);
        LDA(afQ, Ac, 1);
        MMA(0, afP);
        LDA(afP, Ac, 2);
        MMA(1, afQ);
        LDA(afQ, Ac, 3);
        MMA(2, afP);
        MMA(3, afQ);
        WAIT_VM0();
        BAR();
    }

    float bv[3];
#pragma unroll
    for (int n = 0; n < 3; n++) bv[n] = bias[n0 + wn * 48 + n * 16 + lr];
#pragma unroll
    for (int mm = 0; mm < 8; mm++)
#pragma unroll
        for (int n = 0; n < 3; n++)
#pragma unroll
            for (int j = 0; j < 4; j++) {
                const size_t row = m0 + wm * 128 + mm * 16 + ls * 4 + j;
                const size_t col = n0 + wn * 48 + n * 16 + lr;
                C[row * N + col] = f2b(acc[mm][n][j] + bv[n]);
            }
}

// ---------------- RoPE on Q,K only (pow-2 indexing) ----------------
__global__ __launch_bounds__(256) void rope_qk(const bf16_t* __restrict__ qkv,
                                               const int* __restrict__ pos_ids,
                                               bf16_t* __restrict__ Qo,
                                               bf16_t* __restrict__ Ko) {
    const size_t gid = (size_t)blockIdx.x * 256 + threadIdx.x;
    const int d8 = (int)(gid & 15);
    const size_t t1 = gid >> 4;
    const int which = (int)(t1 & 1);
    const size_t t2 = t1 >> 1;
    const int nh = (int)(t2 & 15);
    const size_t bs = t2 >> 4;                  // b*S + s
    const int s = (int)(bs & (S_ - 1));
    const int b = (int)(bs >> 11);

    const bf16_t* src = qkv + bs * (3 * H_) + nh * 384 + which * 128 + d8 * 8;
    bf16x8 xv = *(const bf16x8*)src;
    const bf16_t* xu = (const bf16_t*)&xv;

    float xf[8];
#pragma unroll
    for (int i = 0; i < 8; i++) xf[i] = b2f(xu[i]);
    const int d0 = d8 * 8;
    if (d0 < 32) {                              // rotary on first 32 dims
        const float pos = (float)pos_ids[bs];
        bf16x8 yv = *(const bf16x8*)(src + ((d0 < 16) ? 16 : -16));
        const bf16_t* yu = (const bf16_t*)&yv;
#pragma unroll
        for (int i = 0; i < 8; i++) {
            const int d = d0 + i;
            const float th = pos * exp2f(-(float)(d & 15) * L2B16);
            const float c = cosf(th), sn = sinf(th);
            const float rot = (d < 16) ? -b2f(yu[i]) : b2f(yu[i]);
            xf[i] = xf[i] * c + rot * sn;
        }
    }
    bf16_t ou[8];
#pragma unroll
    for (int i = 0; i < 8; i++) ou[i] = f2b(xf[i]);
    bf16_t* dst = ((which == 0) ? Qo : Ko) + ((size_t)(b * NH_ + nh) * S_ + s) * HS_ + d0;
    *(bf16x8*)dst = *(const bf16x8*)ou;
}

// ---------------- V transpose: (b,s,h,d) -> (bh, d, s), LDS-tiled ----------
__global__ __launch_bounds__(256) void vxpose(const bf16_t* __restrict__ qkv,
                                              bf16_t* __restrict__ Vt) {
    __shared__ bf16_t t[128][130];
    const int bh = (int)blockIdx.x >> 4;
    const int s0 = ((int)blockIdx.x & 15) << 7;
    const int b = bh >> 4, h = bh & 15;
    const int tid = threadIdx.x;

    const int dc = tid & 15, sl = tid >> 4;     // sl 0..15
    const bf16_t* src = qkv + ((size_t)b * S_ + s0) * (3 * H_) + h * 384 + 256 + dc * 8;
#pragma unroll
    for (int c = 0; c < 8; c++) {
        const int s = sl + c * 16;
        bf16x8 v = *(const bf16x8*)(src + (size_t)s * (3 * H_));
        *(bf16x8*)&t[s][dc * 8] = v;
    }
    __syncthreads();
    const int sc = tid & 15, dl = tid >> 4;     // dl 0..15
    bf16_t* dst = Vt + ((size_t)bh * HS_) * S_ + s0 + sc * 8;
#pragma unroll
    for (int c = 0; c < 8; c++) {
        const int d = dl + c * 16;
        bf16_t o[8];
#pragma unroll
        for (int i = 0; i < 8; i++) o[i] = t[sc * 8 + i][d];
        *(bf16x8*)(dst + (size_t)d * S_) = *(const bf16x8*)o;
    }
}

// ---------------- causal flash attention v2 (bisected) ----------------
// Swapped QK^T: sacc = mfma(K-frag, Q-frag) -> lane(lr,ls) holds
// S[q = q0+wid*16+lr][kv = kv0 + t*16 + ls*4 + j].
// Row softmax: in-lane over 16 + 2 shfl_xor over the ls-group.
// P packed with known-good f2b (no cvtpk asm this round).
// Rescale skipped only when EXACTLY identity (rmax <= mrun for all lanes).
__device__ __forceinline__ void attn_stage(bf16_t* Kd, bf16_t* Vd,
                                           const bf16_t* Kg, const bf16_t* Vg,
                                           int kv0, int wid, int lane) {
#pragma unroll
    for (int jj = 0; jj < 4; jj++) {
        const int c = (wid << 2) + jj;
        const int rk = (c << 2) + (lane >> 4);        // K row 0..63
        async16(Kd + c * 512,
                Kg + (size_t)(kv0 + rk) * HS_ + (((lane & 15) ^ (rk & 7)) << 3));
        const int rv = (c << 3) + (lane >> 3);        // V^T row 0..127
        async16(Vd + c * 512,
                Vg + (size_t)rv * S_ + kv0 + (((lane & 7) ^ (rv & 7)) << 3));
    }
}

__global__ __launch_bounds__(256) void attn_fwd(const bf16_t* __restrict__ Q,
                                                const bf16_t* __restrict__ Kv,
                                                const bf16_t* __restrict__ Vt,
                                                const float* __restrict__ amask,
                                                bf16_t* __restrict__ ctx) {
    __shared__ __align__(16) bf16_t Ks[2][64 * 128];
    __shared__ __align__(16) bf16_t Vs[2][128 * 64];
    __shared__ __align__(16) bf16_t Ps[4][16 * 72];

    const int id = (int)(blockIdx.x + (blockIdx.y << 4));     // 0..511
    const int wg = ((id & 7) << 6) + (id >> 3);               // XCD-bijective
    const int pair = wg & 15;
    const int bh = wg >> 4;
    const int b = bh >> 4, h = bh & 15;
    const int tid = threadIdx.x, wid = tid >> 6, lane = tid & 63;
    const int lr = lane & 15, ls = lane >> 4;
    const float* am = amask + (size_t)b * S_;
    const bf16_t* Kg = Kv + (size_t)bh * S_ * HS_;
    const bf16_t* Vg = Vt + (size_t)bh * HS_ * S_;

#pragma unroll 1
    for (int half = 0; half < 2; ++half) {
        const int qt = half ? pair : (31 - pair);
        const int q0 = qt << 6;
        const int qrow = q0 + wid * 16 + lr;     // this lane's q-row

        bf16x8 qf[4];
        const bf16_t* qp = Q + ((size_t)bh * S_ + qrow) * HS_;
#pragma unroll
        for (int dk = 0; dk < 4; dk++) qf[dk] = *(const bf16x8*)(qp + dk * 32 + ls * 8);

        float mrun = -3.0e38f, lrun = 0.f;
        f32x4 oacc[8];
#pragma unroll
        for (int dt = 0; dt < 8; dt++) oacc[dt] = (f32x4){0.f, 0.f, 0.f, 0.f};

        attn_stage(Ks[0], Vs[0], Kg, Vg, 0, wid, lane);

#pragma unroll 1
        for (int step = 0; step <= qt; ++step) {
            const int cur = step & 1;
            const int kv0 = step << 6;
            if (step < qt) {
                attn_stage(Ks[cur ^ 1], Vs[cur ^ 1], Kg, Vg, (step + 1) << 6, wid, lane);
                WAIT_VM8();
            } else {
                WAIT_VM0();
            }
            BAR();

            // swapped QK^T
            f32x4 sacc[4];
#pragma unroll
            for (int t = 0; t < 4; t++) sacc[t] = (f32x4){0.f, 0.f, 0.f, 0.f};
#pragma unroll
            for (int t = 0; t < 4; t++)
#pragma unroll
                for (int dk = 0; dk < 4; dk++) {
                    const int row = t * 16 + lr;
                    bf16x8 kf = *(const bf16x8*)
                        &Ks[cur][row * 128 + (((dk * 4 + ls) ^ (row & 7)) << 3)];
                    sacc[t] = mfma16(kf, qf[dk], sacc[t]);
                }

            const bool diag = (step == qt);
            float sv[4][4];
            float rmax = -3.0e38f;
#pragma unroll
            for (int t = 0; t < 4; t++) {
                const float4 amv = *(const float4*)&am[kv0 + t * 16 + ls * 4];
                const float amj[4] = { amv.x, amv.y, amv.z, amv.w };
#pragma unroll
                for (int j = 0; j < 4; j++) {
                    const int kvp = kv0 + t * 16 + ls * 4 + j;
                    float v = sacc[t][j] * NORM_ + amj[j];
                    if (diag && kvp > qrow) v = -3.0e38f;
                    sv[t][j] = v;
                    rmax = fmaxf(rmax, v);
                }
            }
            rmax = fmaxf(rmax, __shfl_xor(rmax, 16));
            rmax = fmaxf(rmax, __shfl_xor(rmax, 32));

            // rescale only when not an exact identity (rmax > mrun somewhere)
            if (!__all((int)(rmax <= mrun))) {
                const float mnew = fmaxf(mrun, rmax);
                const float sc = __expf(mrun - mnew);
                lrun *= sc;
                mrun = mnew;
                float scb[4];
#pragma unroll
                for (int j = 0; j < 4; j++) scb[j] = __shfl(sc, ls * 4 + j);
#pragma unroll
                for (int dt = 0; dt < 8; dt++)
#pragma unroll
                    for (int j = 0; j < 4; j++) oacc[dt][j] *= scb[j];
            }

            // P = exp(S - mrun), f2b-packed pairs -> ds_write_b32
            float psum = 0.f;
#pragma unroll
            for (int t = 0; t < 4; t++) {
                const float p0 = __expf(sv[t][0] - mrun);
                const float p1 = __expf(sv[t][1] - mrun);
                const float p2 = __expf(sv[t][2] - mrun);
                const float p3 = __expf(sv[t][3] - mrun);
                psum += (p0 + p1) + (p2 + p3);
                const unsigned pk0 = (unsigned)f2b(p0) | ((unsigned)f2b(p1) << 16);
                const unsigned pk1 = (unsigned)f2b(p2) | ((unsigned)f2b(p3) << 16);
                *(unsigned*)&Ps[wid][lr * 72 + t * 16 + ls * 4]     = pk0;
                *(unsigned*)&Ps[wid][lr * 72 + t * 16 + ls * 4 + 2] = pk1;
            }
            psum += __shfl_xor(psum, 16);
            psum += __shfl_xor(psum, 32);
            lrun += psum;

            bf16x8 pf[2];
#pragma unroll
            for (int hh = 0; hh < 2; hh++)
                pf[hh] = *(const bf16x8*)&Ps[wid][lr * 72 + hh * 32 + ls * 8];
#pragma unroll
            for (int dt = 0; dt < 8; dt++)
#pragma unroll
                for (int hh = 0; hh < 2; hh++) {
                    const int vrow = dt * 16 + lr;
                    bf16x8 vf = *(const bf16x8*)
                        &Vs[cur][vrow * 64 + (((hh * 4 + ls) ^ (vrow & 7)) << 3)];
                    oacc[dt] = mfma16(pf[hh], vf, oacc[dt]);
                }
            BAR();
        }

        const float inv = 1.0f / lrun;           // q=lr layout
        float invj[4];
#pragma unroll
        for (int j = 0; j < 4; j++) invj[j] = __shfl(inv, ls * 4 + j);
#pragma unroll
        for (int j = 0; j < 4; j++) {
            bf16_t* dst = ctx + ((size_t)b * S_ + q0 + wid * 16 + ls * 4 + j) * H_ + h * HS_;
#pragma unroll
            for (int dt = 0; dt < 8; dt++) dst[dt * 16 + lr] = f2b(oacc[dt][j] * invj[j]);
        }
    }
}

extern "C" void kernel_launch(void* const* d_in, const int* in_sizes, int n_in,
                              void* d_out, int out_size, void* d_ws, size_t ws_size,
                              hipStream_t stream) {
    const float* hs   = (const float*)d_in[0];
    const float* am   = (const float*)d_in[1];
    const int*   pos  = (const int*)d_in[2];
    const float* Wqkv = (const float*)d_in[3];
    const float* bqkv = (const float*)d_in[4];
    const float* Wd   = (const float*)d_in[5];
    const float* bd   = (const float*)d_in[6];
    float* out = (float*)d_out;
    char*  ws  = (char*)d_ws;

    const size_t MB = 1024 * 1024;
    bf16_t* X    = (bf16_t*)(ws);              // 16 MB (reused as ctx)
    bf16_t* WqT  = (bf16_t*)(ws + 16 * MB);    // 24 MB
    bf16_t* WdT  = (bf16_t*)(ws + 40 * MB);    // 8 MB
    bf16_t* QKVb = (bf16_t*)(ws + 48 * MB);    // 48 MB
    bf16_t* Qb   = (bf16_t*)(ws + 96 * MB);    // 16 MB
    bf16_t* Kb   = (bf16_t*)(ws + 112 * MB);   // 16 MB
    bf16_t* Vtb  = (bf16_t*)(ws + 128 * MB);   // 16 MB
    bf16_t* ctx  = X;

    cvt_bf16<<<4096, 256, 0, stream>>>(hs, X);
    transpose_cvt<<<dim3(6144 / 32, 2048 / 32), 256, 0, stream>>>(Wqkv, WqT, 2048, 6144);
    transpose_cvt<<<dim3(2048 / 32, 2048 / 32), 256, 0, stream>>>(Wd, WdT, 2048, 2048);
    gemm_qkv<<<dim3(32, 16), 512, 0, stream>>>(X, WqT, bqkv, QKVb, 4096, 6144, 2048);
    rope_qk<<<8192, 256, 0, stream>>>(QKVb, pos, Qb, Kb);
    vxpose<<<512, 256, 0, stream>>>(QKVb, Vtb);
    attn_fwd<<<dim3(16, 32), 256, 0, stream>>>(Qb, Kb, Vtb, am, ctx);
    gemm_bias<0><<<dim3(2048 / 128, 4096 / 128), 256, 0, stream>>>(ctx, WdT, bd, out,
                                                                   4096, 2048, 2048);
}